// Round 1
// baseline (4997.808 us; speedup 1.0000x reference)
//
#include <hip/hip_runtime.h>
#include <math.h>

#define BB 8
#define CIN 32
#define NN 10000
#define TTT 12
#define EE 160000
#define CSP 64
#define BT (BB*TTT)   // 96
#define EPSV 1e-5f

static __device__ __forceinline__ float sigmoidf_(float v) {
    return __builtin_amdgcn_rcpf(1.f + __expf(-v));
}

// ---------------- graph preprocessing ----------------
__global__ void k_deg(const int* __restrict__ ei, const float* __restrict__ ew,
                      float* __restrict__ deg) {
    int e = blockIdx.x * 256 + threadIdx.x;
    if (e < EE) atomicAdd(&deg[ei[e]], ew[e]);
}

__global__ void k_dinv(float* __restrict__ deg) {
    int n = blockIdx.x * 256 + threadIdx.x;
    if (n < NN) { float d = deg[n]; deg[n] = d > 0.f ? rsqrtf(d) : 0.f; }
}

__global__ void k_norm_cnt(const int* __restrict__ ei, const float* __restrict__ ew,
                           const float* __restrict__ dinv, float* __restrict__ nrm,
                           int* __restrict__ cnt) {
    int e = blockIdx.x * 256 + threadIdx.x;
    if (e < EE) {
        int r = ei[e], c = ei[EE + e];
        nrm[e] = -ew[e] * dinv[r] * dinv[c];
        atomicAdd(&cnt[c], 1);
    }
}

__global__ void k_scan(const int* __restrict__ cnt, int* __restrict__ offs,
                       int* __restrict__ cursor) {
    __shared__ int sh[1024];
    int tid = threadIdx.x;
    int running = 0;
    for (int base = 0; base < NN; base += 1024) {
        int i = base + tid;
        int v = (i < NN) ? cnt[i] : 0;
        sh[tid] = v;
        __syncthreads();
        for (int off = 1; off < 1024; off <<= 1) {
            int t = (tid >= off) ? sh[tid - off] : 0;
            __syncthreads();
            sh[tid] += t;
            __syncthreads();
        }
        int incl = sh[tid];
        if (i < NN) { offs[i] = running + incl - v; cursor[i] = running + incl - v; }
        int ct = sh[1023];
        __syncthreads();
        running += ct;
    }
    if (tid == 0) offs[NN] = running;
}

__global__ void k_fill(const int* __restrict__ ei, const float* __restrict__ nrm,
                       int* __restrict__ cursor, int* __restrict__ csr_src,
                       float* __restrict__ csr_w) {
    int e = blockIdx.x * 256 + threadIdx.x;
    if (e < EE) {
        int cdst = ei[EE + e];
        int p = atomicAdd(&cursor[cdst], 1);
        csr_src[p] = ei[e];
        csr_w[p] = nrm[e];
    }
}

// ---------------- temporal block 1 ----------------
// grid: BB * NN/4 blocks of 256 (4 waves = 4 nodes, lane = out channel)
__global__ __launch_bounds__(256) void k_tconv1(
    const float* __restrict__ x, const float* __restrict__ wg, const float* __restrict__ bg,
    const float* __restrict__ gam, const float* __restrict__ bet,
    const float* __restrict__ mean, const float* __restrict__ var,
    float* __restrict__ h1)
{
    __shared__ float wl[96 * 128];      // [(cin*3+k)][cc]
    __shared__ float xs[4][32][14];     // padded time
    int bi = blockIdx.x;
    int b = bi / (NN / 4);
    int n0 = (bi % (NN / 4)) * 4;
    int tid = threadIdx.x;

#pragma unroll
    for (int j = 0; j < 48; ++j) {
        int i = tid + j * 256;          // 12288 weights
        int cc = i / 96, r = i - cc * 96;
        wl[r * 128 + cc] = wg[i];
    }
    if (tid < 128) {
        int nd = tid >> 5, ci = tid & 31;
        const float* src = x + ((size_t)(b * CIN + ci) * NN + (n0 + nd)) * TTT;
        float4 a0 = *(const float4*)(src);
        float4 a1 = *(const float4*)(src + 4);
        float4 a2 = *(const float4*)(src + 8);
        float* d = &xs[nd][ci][0];
        d[0] = 0.f; d[13] = 0.f;
        d[1] = a0.x; d[2] = a0.y; d[3] = a0.z; d[4] = a0.w;
        d[5] = a1.x; d[6] = a1.y; d[7] = a1.z; d[8] = a1.w;
        d[9] = a2.x; d[10] = a2.y; d[11] = a2.z; d[12] = a2.w;
    }
    __syncthreads();

    int c = tid & 63, nd = tid >> 6;
    float p[12], q[12];
#pragma unroll
    for (int t = 0; t < 12; ++t) { p[t] = 0.f; q[t] = 0.f; }

    for (int ci = 0; ci < 32; ++ci) {
        float xv[14];
#pragma unroll
        for (int t = 0; t < 14; ++t) xv[t] = xs[nd][ci][t];
#pragma unroll
        for (int k = 0; k < 3; ++k) {
            float wp = wl[(ci * 3 + k) * 128 + c];
            float wq = wl[(ci * 3 + k) * 128 + 64 + c];
#pragma unroll
            for (int t = 0; t < 12; ++t) {
                p[t] = fmaf(wp, xv[t + k], p[t]);
                q[t] = fmaf(wq, xv[t + k], q[t]);
            }
        }
    }
    float bp = bg[c], bq = bg[64 + c];
    float sc = gam[c] * rsqrtf(var[c] + EPSV);
    float mn = mean[c], be = bet[c];
    int n = n0 + nd;
#pragma unroll
    for (int t = 0; t < 12; ++t) {
        float h = (p[t] + bp) * sigmoidf_(q[t] + bq);
        h1[((size_t)(b * TTT + t) * NN + n) * 64 + c] = (h - mn) * sc + be;
    }
}

// ---------------- gather 1: G = lhat(h1) ----------------
__global__ __launch_bounds__(256) void k_gather1(
    const float* __restrict__ h1, const int* __restrict__ offs,
    const int* __restrict__ src, const float* __restrict__ w,
    float* __restrict__ G)
{
    int bi = blockIdx.x;
    int bt = bi / (NN / 4);
    int n = (bi % (NN / 4)) * 4 + (threadIdx.x >> 6);
    int c = threadIdx.x & 63;
    int o0 = offs[n], o1 = offs[n + 1];
    const float* base = h1 + (size_t)bt * NN * 64;
    float acc0 = 0.f, acc1 = 0.f;
    int i = o0;
    for (; i + 1 < o1; i += 2) {
        int s0 = src[i], s1 = src[i + 1];
        float w0 = w[i], w1 = w[i + 1];
        acc0 = fmaf(w0, base[s0 * 64 + c], acc0);
        acc1 = fmaf(w1, base[s1 * 64 + c], acc1);
    }
    if (i < o1) acc0 = fmaf(w[i], base[src[i] * 64 + c], acc0);
    G[(size_t)bt * NN * 64 + n * 64 + c] = acc0 + acc1;
}

// ---------------- per-node einsums ----------------
// o = a@(W0-W2) + g@W1 + b ; u = g@W2 ; h1<-o, G<-u
__global__ __launch_bounds__(256) void k_cheb_mm(
    float* __restrict__ h1, float* __restrict__ G,
    const float* __restrict__ cw, const float* __restrict__ cb)
{
    __shared__ float w02[4096], w1s[4096], w2s[4096];
    __shared__ float ash[4][64], gsh[4][64];
    int tid = threadIdx.x;
#pragma unroll
    for (int j = 0; j < 16; ++j) {
        int i = tid + j * 256;
        float a0 = cw[i], a1 = cw[4096 + i], a2 = cw[8192 + i];
        w02[i] = a0 - a2; w1s[i] = a1; w2s[i] = a2;
    }
    int bi = blockIdx.x;
    int bt = bi / 250;
    int nbase = (bi % 250) * 40;
    int c = tid & 63, nd = tid >> 6;
    float bc = cb[c];
    for (int it = 0; it < 10; ++it) {
        int n = nbase + it * 4;
        __syncthreads();
        {
            int node = tid >> 6, cc = tid & 63;
            size_t idx = (size_t)bt * NN * 64 + (size_t)(n + node) * 64 + cc;
            ash[node][cc] = h1[idx];
            gsh[node][cc] = G[idx];
        }
        __syncthreads();
        float o = bc, u = 0.f;
#pragma unroll 8
        for (int ci = 0; ci < 64; ++ci) {
            float av = ash[nd][ci], gv = gsh[nd][ci];
            o = fmaf(av, w02[ci * 64 + c], o);
            o = fmaf(gv, w1s[ci * 64 + c], o);
            u = fmaf(gv, w2s[ci * 64 + c], u);
        }
        size_t idx = (size_t)bt * NN * 64 + (size_t)(n + nd) * 64 + c;
        h1[idx] = o;
        G[idx] = u;
    }
}

// ---------------- gather 2 + LayerNorm + ReLU (in place on h1) ----------------
__global__ __launch_bounds__(256) void k_gather2_ln(
    float* __restrict__ h1, const float* __restrict__ G, const int* __restrict__ offs,
    const int* __restrict__ src, const float* __restrict__ w,
    const float* __restrict__ lng, const float* __restrict__ lnb)
{
    int bi = blockIdx.x;
    int bt = bi / (NN / 4);
    int n = (bi % (NN / 4)) * 4 + (threadIdx.x >> 6);
    int c = threadIdx.x & 63;
    int o0 = offs[n], o1 = offs[n + 1];
    const float* base = G + (size_t)bt * NN * 64;
    size_t idx = (size_t)bt * NN * 64 + (size_t)n * 64 + c;
    float acc0 = h1[idx], acc1 = 0.f;
    int i = o0;
    for (; i + 1 < o1; i += 2) {
        int s0 = src[i], s1 = src[i + 1];
        float w0 = 2.f * w[i], w1 = 2.f * w[i + 1];
        acc0 = fmaf(w0, base[s0 * 64 + c], acc0);
        acc1 = fmaf(w1, base[s1 * 64 + c], acc1);
    }
    if (i < o1) acc0 = fmaf(2.f * w[i], base[src[i] * 64 + c], acc0);
    float acc = acc0 + acc1;
    float s1v = acc, s2v = acc * acc;
#pragma unroll
    for (int m = 32; m >= 1; m >>= 1) {
        s1v += __shfl_xor(s1v, m, 64);
        s2v += __shfl_xor(s2v, m, 64);
    }
    float mu = s1v * (1.f / 64.f);
    float vr = s2v * (1.f / 64.f) - mu * mu;
    float y = (acc - mu) * rsqrtf(vr + EPSV) * lng[c] + lnb[c];
    h1[idx] = fmaxf(y, 0.f);
}

// ---------------- temporal block 2 + residual ----------------
__global__ __launch_bounds__(256) void k_tconv2(
    const float* __restrict__ h1, const float* __restrict__ x,
    const float* __restrict__ wg, const float* __restrict__ bg,
    const float* __restrict__ gam, const float* __restrict__ bet,
    const float* __restrict__ mean, const float* __restrict__ var,
    const float* __restrict__ wres, const float* __restrict__ bres,
    float* __restrict__ out)
{
    __shared__ float smem[12288 + 4 * 64 * 14];   // wl (49KB) + hs (14KB)
    float* wl = smem;             // [(cin*3+k)*64 + c], one GLU half at a time
    float* hs = smem + 12288;     // [node][cin][14] padded time
    int bi = blockIdx.x;
    int b = bi / (NN / 4);
    int n0 = (bi % (NN / 4)) * 4;
    int tid = threadIdx.x;
    int c = tid & 63, nd = tid >> 6;

    // stage h tile: 4 nodes x 12 t x 64 c
#pragma unroll
    for (int j = 0; j < 12; ++j) {
        int flat = tid + j * 256;          // 0..3071
        int cc = flat & 63;
        int row = flat >> 6;               // 0..47
        int ndd = row / 12, t = row - ndd * 12;
        hs[(ndd * 64 + cc) * 14 + t + 1] =
            h1[((size_t)(b * TTT + t) * NN + (n0 + ndd)) * 64 + cc];
    }
    hs[(nd * 64 + c) * 14 + 0] = 0.f;
    hs[(nd * 64 + c) * 14 + 13] = 0.f;

    // ---- p half ----
#pragma unroll
    for (int j = 0; j < 48; ++j) {
        int i = tid + j * 256;             // 12288
        int cc = i / 192, r = i - cc * 192;
        wl[r * 64 + cc] = wg[i];
    }
    __syncthreads();
    float p[12];
#pragma unroll
    for (int t = 0; t < 12; ++t) p[t] = 0.f;
    for (int ci = 0; ci < 64; ++ci) {
        float xv[14];
#pragma unroll
        for (int t = 0; t < 14; ++t) xv[t] = hs[(nd * 64 + ci) * 14 + t];
#pragma unroll
        for (int k = 0; k < 3; ++k) {
            float wv = wl[(ci * 3 + k) * 64 + c];
#pragma unroll
            for (int t = 0; t < 12; ++t) p[t] = fmaf(wv, xv[t + k], p[t]);
        }
    }
    __syncthreads();

    // ---- q half ----
#pragma unroll
    for (int j = 0; j < 48; ++j) {
        int i = tid + j * 256;
        int cc = i / 192, r = i - cc * 192;
        wl[r * 64 + cc] = wg[12288 + i];
    }
    __syncthreads();
    float q[12];
#pragma unroll
    for (int t = 0; t < 12; ++t) q[t] = 0.f;
    for (int ci = 0; ci < 64; ++ci) {
        float xv[14];
#pragma unroll
        for (int t = 0; t < 14; ++t) xv[t] = hs[(nd * 64 + ci) * 14 + t];
#pragma unroll
        for (int k = 0; k < 3; ++k) {
            float wv = wl[(ci * 3 + k) * 64 + c];
#pragma unroll
            for (int t = 0; t < 12; ++t) q[t] = fmaf(wv, xv[t + k], q[t]);
        }
    }
    __syncthreads();

    // ---- residual: reuse wl space for x tile ----
    float* xs = wl;   // [node][cin][12]
    if (tid < 128) {
        int ndd = tid >> 5, ci = tid & 31;
        const float* sp = x + ((size_t)(b * CIN + ci) * NN + (n0 + ndd)) * TTT;
        float4 a0 = *(const float4*)(sp);
        float4 a1 = *(const float4*)(sp + 4);
        float4 a2 = *(const float4*)(sp + 8);
        float* d = xs + (ndd * 32 + ci) * 12;
        d[0] = a0.x; d[1] = a0.y; d[2] = a0.z; d[3] = a0.w;
        d[4] = a1.x; d[5] = a1.y; d[6] = a1.z; d[7] = a1.w;
        d[8] = a2.x; d[9] = a2.y; d[10] = a2.z; d[11] = a2.w;
    }
    __syncthreads();
    float r[12];
#pragma unroll
    for (int t = 0; t < 12; ++t) r[t] = 0.f;
    for (int ci = 0; ci < 32; ++ci) {
        float wv = wres[c * 32 + ci];
#pragma unroll
        for (int t = 0; t < 12; ++t) r[t] = fmaf(wv, xs[(nd * 32 + ci) * 12 + t], r[t]);
    }

    float bp = bg[c], bq = bg[64 + c];
    float sc = gam[c] * rsqrtf(var[c] + EPSV);
    float mn = mean[c], be = bet[c], br = bres[c];
    float o[12];
#pragma unroll
    for (int t = 0; t < 12; ++t) {
        float h = (p[t] + bp) * sigmoidf_(q[t] + bq);
        o[t] = (h - mn) * sc + be + r[t] + br;
    }
    float* op = out + ((size_t)(b * 64 + c) * NN + (n0 + nd)) * TTT;
    *(float4*)(op)     = make_float4(o[0], o[1], o[2], o[3]);
    *(float4*)(op + 4) = make_float4(o[4], o[5], o[6], o[7]);
    *(float4*)(op + 8) = make_float4(o[8], o[9], o[10], o[11]);
}

extern "C" void kernel_launch(void* const* d_in, const int* in_sizes, int n_in,
                              void* d_out, int out_size, void* d_ws, size_t ws_size,
                              hipStream_t stream)
{
    const float* x   = (const float*)d_in[0];
    const int*   ei  = (const int*)d_in[1];
    const float* ew  = (const float*)d_in[2];
    const float* wg1 = (const float*)d_in[3];
    const float* bg1 = (const float*)d_in[4];
    const float* g1  = (const float*)d_in[5];
    const float* be1 = (const float*)d_in[6];
    const float* m1  = (const float*)d_in[7];
    const float* v1  = (const float*)d_in[8];
    const float* cw  = (const float*)d_in[9];
    const float* cb  = (const float*)d_in[10];
    const float* lng = (const float*)d_in[11];
    const float* lnb = (const float*)d_in[12];
    const float* wg2 = (const float*)d_in[13];
    const float* bg2 = (const float*)d_in[14];
    const float* g2  = (const float*)d_in[15];
    const float* be2 = (const float*)d_in[16];
    const float* m2  = (const float*)d_in[17];
    const float* v2  = (const float*)d_in[18];
    const float* wr  = (const float*)d_in[19];
    const float* br  = (const float*)d_in[20];

    char* w = (char*)d_ws;
    float* h1     = (float*)w;  w += (size_t)BT * NN * 64 * 4;   // 245.76 MB
    float* deg    = (float*)w;  w += NN * 4;
    int*   cnt    = (int*)w;    w += NN * 4;
    int*   offs   = (int*)w;    w += (NN + 1) * 4;
    int*   cursor = (int*)w;    w += NN * 4;
    float* nrm    = (float*)w;  w += EE * 4;
    int*   csrs   = (int*)w;    w += EE * 4;
    float* csrw   = (float*)w;  w += EE * 4;
    float* G = (float*)d_out;   // reuse output buffer as Cheb scratch field

    hipMemsetAsync(deg, 0, NN * 4 * 2, stream);   // deg + cnt

    k_deg<<<625, 256, 0, stream>>>(ei, ew, deg);
    k_dinv<<<40, 256, 0, stream>>>(deg);
    k_norm_cnt<<<625, 256, 0, stream>>>(ei, ew, deg, nrm, cnt);
    k_scan<<<1, 1024, 0, stream>>>(cnt, offs, cursor);
    k_fill<<<625, 256, 0, stream>>>(ei, nrm, cursor, csrs, csrw);

    k_tconv1<<<BB * (NN / 4), 256, 0, stream>>>(x, wg1, bg1, g1, be1, m1, v1, h1);
    k_gather1<<<BT * (NN / 4), 256, 0, stream>>>(h1, offs, csrs, csrw, G);
    k_cheb_mm<<<BT * 250, 256, 0, stream>>>(h1, G, cw, cb);
    k_gather2_ln<<<BT * (NN / 4), 256, 0, stream>>>(h1, G, offs, csrs, csrw, lng, lnb);
    k_tconv2<<<BB * (NN / 4), 256, 0, stream>>>(h1, x, wg2, bg2, g2, be2, m2, v2, wr, br,
                                                (float*)d_out);
}

// Round 2
// 3135.223 us; speedup vs baseline: 1.5941x; 1.5941x over previous
//
#include <hip/hip_runtime.h>
#include <math.h>

#define BB 8
#define CIN 32
#define NN 10000
#define TTT 12
#define EE 160000
#define CSP 64
#define BT (BB*TTT)   // 96
#define EPSV 1e-5f

typedef __attribute__((ext_vector_type(8))) short bf16x8;
typedef __attribute__((ext_vector_type(4))) float f32x4;

static __device__ __forceinline__ float sigmoidf_(float v) {
    return __builtin_amdgcn_rcpf(1.f + __expf(-v));
}

static __device__ __forceinline__ short f2bf(float v) {
    unsigned u = __float_as_uint(v);
    u = (u + 0x7fffu + ((u >> 16) & 1u)) >> 16;
    return (short)u;
}

// ---------------- graph preprocessing ----------------
__global__ void k_deg(const int* __restrict__ ei, const float* __restrict__ ew,
                      float* __restrict__ deg) {
    int e = blockIdx.x * 256 + threadIdx.x;
    if (e < EE) atomicAdd(&deg[ei[e]], ew[e]);
}

__global__ void k_dinv(float* __restrict__ deg) {
    int n = blockIdx.x * 256 + threadIdx.x;
    if (n < NN) { float d = deg[n]; deg[n] = d > 0.f ? rsqrtf(d) : 0.f; }
}

__global__ void k_norm_cnt(const int* __restrict__ ei, const float* __restrict__ ew,
                           const float* __restrict__ dinv, float* __restrict__ nrm,
                           int* __restrict__ cnt) {
    int e = blockIdx.x * 256 + threadIdx.x;
    if (e < EE) {
        int r = ei[e], c = ei[EE + e];
        nrm[e] = -ew[e] * dinv[r] * dinv[c];
        atomicAdd(&cnt[c], 1);
    }
}

__global__ void k_scan(const int* __restrict__ cnt, int* __restrict__ offs,
                       int* __restrict__ cursor) {
    __shared__ int sh[1024];
    int tid = threadIdx.x;
    int running = 0;
    for (int base = 0; base < NN; base += 1024) {
        int i = base + tid;
        int v = (i < NN) ? cnt[i] : 0;
        sh[tid] = v;
        __syncthreads();
        for (int off = 1; off < 1024; off <<= 1) {
            int t = (tid >= off) ? sh[tid - off] : 0;
            __syncthreads();
            sh[tid] += t;
            __syncthreads();
        }
        int incl = sh[tid];
        if (i < NN) { offs[i] = running + incl - v; cursor[i] = running + incl - v; }
        int ct = sh[1023];
        __syncthreads();
        running += ct;
    }
    if (tid == 0) offs[NN] = running;
}

__global__ void k_fill(const int* __restrict__ ei, const float* __restrict__ nrm,
                       int* __restrict__ cursor, int* __restrict__ csr_src,
                       float* __restrict__ csr_w) {
    int e = blockIdx.x * 256 + threadIdx.x;
    if (e < EE) {
        int cdst = ei[EE + e];
        int p = atomicAdd(&cursor[cdst], 1);
        csr_src[p] = ei[e];
        csr_w[p] = nrm[e];
    }
}

// ---------------- weight conversion to bf16 ----------------
__global__ void k_cvt_w(const float* __restrict__ wg1, const float* __restrict__ wg2,
                        const float* __restrict__ wr,
                        short* __restrict__ o1, short* __restrict__ o2,
                        short* __restrict__ o3) {
    int i = blockIdx.x * 256 + threadIdx.x;
    if (i < 12288) o1[i] = f2bf(wg1[i]);
    if (i < 24576) o2[i] = f2bf(wg2[i]);
    if (i < 2048)  o3[i] = f2bf(wr[i]);
}

// ---------------- temporal block 1 (MFMA) ----------------
// D[(n,t)][c_out] = im2col^T @ W^T ; 48 cols x 128 c_out per block (4 nodes)
__global__ __launch_bounds__(256, 4) void k_tconv1_mfma(
    const float* __restrict__ x, const short* __restrict__ wbf,
    const float* __restrict__ bg, const float* __restrict__ gam,
    const float* __restrict__ bet, const float* __restrict__ mean,
    const float* __restrict__ var, float* __restrict__ h1)
{
    __shared__ short Btl[3 * 48 * 40];   // im2col bf16, K-subtiled
    int bi = blockIdx.x;
    int b = bi / 2500;
    int n0 = (bi % 2500) * 4;
    int tid = threadIdx.x;

    // stage x -> im2col (K = ci*3+kk, col = n*12+t')
    for (int j = tid; j < 384; j += 256) {
        int ci = j / 12, r = j - ci * 12;
        const float* xp = x + ((size_t)(b * CIN + ci) * NN + n0) * 12 + r * 4;
        float4 v = *(const float4*)xp;
        float vv[4] = {v.x, v.y, v.z, v.w};
#pragma unroll
        for (int e = 0; e < 4; ++e) {
            int at = r * 4 + e;            // 0..47
            int n = at / 12, t = at - n * 12;
            short bv = f2bf(vv[e]);
#pragma unroll
            for (int kk = 0; kk < 3; ++kk) {
                int tp = t + 1 - kk;
                if (tp >= 0 && tp < 12) {
                    int K = ci * 3 + kk;
                    Btl[((K >> 5) * 48 + n * 12 + tp) * 40 + (K & 31)] = bv;
                }
            }
            if (t == 0)  { int K = ci * 3;     Btl[((K >> 5) * 48 + n * 12) * 40 + (K & 31)] = 0; }
            if (t == 11) { int K = ci * 3 + 2; Btl[((K >> 5) * 48 + n * 12 + 11) * 40 + (K & 31)] = 0; }
        }
    }
    __syncthreads();

    int w = tid >> 6, l = tid & 63, lr = l & 15, lq = l >> 4;
    f32x4 aP[3], aQ[3];
#pragma unroll
    for (int m = 0; m < 3; ++m) { aP[m] = (f32x4){0,0,0,0}; aQ[m] = (f32x4){0,0,0,0}; }

#pragma unroll
    for (int ks = 0; ks < 3; ++ks) {
        bf16x8 wp = *(const bf16x8*)(wbf + ((w * 16 + lr) * 96 + ks * 32 + lq * 8));
        bf16x8 wq = *(const bf16x8*)(wbf + ((64 + w * 16 + lr) * 96 + ks * 32 + lq * 8));
#pragma unroll
        for (int mt = 0; mt < 3; ++mt) {
            bf16x8 im = *(const bf16x8*)(&Btl[(ks * 48 + mt * 16 + lr) * 40 + lq * 8]);
            aP[mt] = __builtin_amdgcn_mfma_f32_16x16x32_bf16(im, wp, aP[mt], 0, 0, 0);
            aQ[mt] = __builtin_amdgcn_mfma_f32_16x16x32_bf16(im, wq, aQ[mt], 0, 0, 0);
        }
    }

    int c = w * 16 + lr;
    float bp = bg[c], bq = bg[64 + c];
    float sc = gam[c] * rsqrtf(var[c] + EPSV);
    float mn = mean[c], be = bet[c];
#pragma unroll
    for (int mt = 0; mt < 3; ++mt) {
#pragma unroll
        for (int j = 0; j < 4; ++j) {
            int row = mt * 16 + lq * 4 + j;     // (n,t)
            int n = n0 + row / 12, t = row % 12;
            float h = (aP[mt][j] + bp) * sigmoidf_(aQ[mt][j] + bq);
            h1[((size_t)(b * TTT + t) * NN + n) * 64 + c] = (h - mn) * sc + be;
        }
    }
}

// ---------------- gather 1: G = lhat(h1) ----------------
__global__ __launch_bounds__(256) void k_gather1(
    const float* __restrict__ h1, const int* __restrict__ offs,
    const int* __restrict__ src, const float* __restrict__ w,
    float* __restrict__ G)
{
    int bi = blockIdx.x;
    int bt = bi / (NN / 4);
    int n = (bi % (NN / 4)) * 4 + (threadIdx.x >> 6);
    int c = threadIdx.x & 63;
    int o0 = offs[n], o1 = offs[n + 1];
    const float* base = h1 + (size_t)bt * NN * 64;
    float acc0 = 0.f, acc1 = 0.f;
    int i = o0;
    for (; i + 1 < o1; i += 2) {
        int s0 = src[i], s1 = src[i + 1];
        float w0 = w[i], w1 = w[i + 1];
        acc0 = fmaf(w0, base[s0 * 64 + c], acc0);
        acc1 = fmaf(w1, base[s1 * 64 + c], acc1);
    }
    if (i < o1) acc0 = fmaf(w[i], base[src[i] * 64 + c], acc0);
    G[(size_t)bt * NN * 64 + n * 64 + c] = acc0 + acc1;
}

// ---------------- per-node einsums ----------------
__global__ __launch_bounds__(256) void k_cheb_mm(
    float* __restrict__ h1, float* __restrict__ G,
    const float* __restrict__ cw, const float* __restrict__ cb)
{
    __shared__ float w02[4096], w1s[4096], w2s[4096];
    __shared__ float ash[4][64], gsh[4][64];
    int tid = threadIdx.x;
#pragma unroll
    for (int j = 0; j < 16; ++j) {
        int i = tid + j * 256;
        float a0 = cw[i], a1 = cw[4096 + i], a2 = cw[8192 + i];
        w02[i] = a0 - a2; w1s[i] = a1; w2s[i] = a2;
    }
    int bi = blockIdx.x;
    int bt = bi / 250;
    int nbase = (bi % 250) * 40;
    int c = tid & 63, nd = tid >> 6;
    float bc = cb[c];
    for (int it = 0; it < 10; ++it) {
        int n = nbase + it * 4;
        __syncthreads();
        {
            int node = tid >> 6, cc = tid & 63;
            size_t idx = (size_t)bt * NN * 64 + (size_t)(n + node) * 64 + cc;
            ash[node][cc] = h1[idx];
            gsh[node][cc] = G[idx];
        }
        __syncthreads();
        float o = bc, u = 0.f;
#pragma unroll 8
        for (int ci = 0; ci < 64; ++ci) {
            float av = ash[nd][ci], gv = gsh[nd][ci];
            o = fmaf(av, w02[ci * 64 + c], o);
            o = fmaf(gv, w1s[ci * 64 + c], o);
            u = fmaf(gv, w2s[ci * 64 + c], u);
        }
        size_t idx = (size_t)bt * NN * 64 + (size_t)(n + nd) * 64 + c;
        h1[idx] = o;
        G[idx] = u;
    }
}

// ---------------- gather 2 + LayerNorm + ReLU ----------------
__global__ __launch_bounds__(256) void k_gather2_ln(
    float* __restrict__ h1, const float* __restrict__ G, const int* __restrict__ offs,
    const int* __restrict__ src, const float* __restrict__ w,
    const float* __restrict__ lng, const float* __restrict__ lnb)
{
    int bi = blockIdx.x;
    int bt = bi / (NN / 4);
    int n = (bi % (NN / 4)) * 4 + (threadIdx.x >> 6);
    int c = threadIdx.x & 63;
    int o0 = offs[n], o1 = offs[n + 1];
    const float* base = G + (size_t)bt * NN * 64;
    size_t idx = (size_t)bt * NN * 64 + (size_t)n * 64 + c;
    float acc0 = h1[idx], acc1 = 0.f;
    int i = o0;
    for (; i + 1 < o1; i += 2) {
        int s0 = src[i], s1 = src[i + 1];
        float w0 = 2.f * w[i], w1 = 2.f * w[i + 1];
        acc0 = fmaf(w0, base[s0 * 64 + c], acc0);
        acc1 = fmaf(w1, base[s1 * 64 + c], acc1);
    }
    if (i < o1) acc0 = fmaf(2.f * w[i], base[src[i] * 64 + c], acc0);
    float acc = acc0 + acc1;
    float s1v = acc, s2v = acc * acc;
#pragma unroll
    for (int m = 32; m >= 1; m >>= 1) {
        s1v += __shfl_xor(s1v, m, 64);
        s2v += __shfl_xor(s2v, m, 64);
    }
    float mu = s1v * (1.f / 64.f);
    float vr = s2v * (1.f / 64.f) - mu * mu;
    float y = (acc - mu) * rsqrtf(vr + EPSV) * lng[c] + lnb[c];
    h1[idx] = fmaxf(y, 0.f);
}

// ---------------- temporal block 2 + residual (MFMA) ----------------
// D[c_out][(n,t)] = W @ im2col ; residual K=32 MFMA vs w_res
__global__ __launch_bounds__(256, 4) void k_tconv2_mfma(
    const float* __restrict__ h1, const float* __restrict__ x,
    const short* __restrict__ wbf, const short* __restrict__ wrbf,
    const float* __restrict__ bg, const float* __restrict__ gam,
    const float* __restrict__ bet, const float* __restrict__ mean,
    const float* __restrict__ var, const float* __restrict__ bres,
    float* __restrict__ out)
{
    __shared__ short Btl[6 * 48 * 40];   // 23040 B
    __shared__ short Bx[48 * 40];        // 3840 B
    int bi = blockIdx.x;
    int b = bi / 2500;
    int n0 = (bi % 2500) * 4;
    int tid = threadIdx.x;

    // stage h1 -> im2col bf16
    {
        int n = tid >> 6, c = tid & 63;
#pragma unroll
        for (int t = 0; t < 12; ++t) {
            float v = h1[((size_t)(b * TTT + t) * NN + n0 + n) * 64 + c];
            short bv = f2bf(v);
#pragma unroll
            for (int kk = 0; kk < 3; ++kk) {
                int tp = t + 1 - kk;
                if (tp >= 0 && tp < 12) {
                    int K = c * 3 + kk;
                    Btl[((K >> 5) * 48 + n * 12 + tp) * 40 + (K & 31)] = bv;
                }
            }
            if (t == 0)  { int K = c * 3;     Btl[((K >> 5) * 48 + n * 12) * 40 + (K & 31)] = 0; }
            if (t == 11) { int K = c * 3 + 2; Btl[((K >> 5) * 48 + n * 12 + 11) * 40 + (K & 31)] = 0; }
        }
    }
    // stage x -> Bx bf16 (col major, ci inner)
    for (int j = tid; j < 384; j += 256) {
        int ci = j / 12, r = j - ci * 12;
        const float* xp = x + ((size_t)(b * CIN + ci) * NN + n0) * 12 + r * 4;
        float4 v = *(const float4*)xp;
        float vv[4] = {v.x, v.y, v.z, v.w};
#pragma unroll
        for (int e = 0; e < 4; ++e) {
            int col = r * 4 + e;            // 0..47
            Bx[col * 40 + ci] = f2bf(vv[e]);
        }
    }
    __syncthreads();

    int w = tid >> 6, l = tid & 63, lr = l & 15, lq = l >> 4;
    f32x4 accP[3], accQ[3], accR[3];
#pragma unroll
    for (int m = 0; m < 3; ++m) {
        accP[m] = (f32x4){0,0,0,0}; accQ[m] = (f32x4){0,0,0,0}; accR[m] = (f32x4){0,0,0,0};
    }

#pragma unroll
    for (int ks = 0; ks < 6; ++ks) {
        bf16x8 aP = *(const bf16x8*)(wbf + ((w * 16 + lr) * 192 + ks * 32 + lq * 8));
        bf16x8 aQ = *(const bf16x8*)(wbf + ((64 + w * 16 + lr) * 192 + ks * 32 + lq * 8));
#pragma unroll
        for (int ct = 0; ct < 3; ++ct) {
            bf16x8 bfr = *(const bf16x8*)(&Btl[(ks * 48 + ct * 16 + lr) * 40 + lq * 8]);
            accP[ct] = __builtin_amdgcn_mfma_f32_16x16x32_bf16(aP, bfr, accP[ct], 0, 0, 0);
            accQ[ct] = __builtin_amdgcn_mfma_f32_16x16x32_bf16(aQ, bfr, accQ[ct], 0, 0, 0);
        }
    }
    {
        bf16x8 aR = *(const bf16x8*)(wrbf + ((w * 16 + lr) * 32 + lq * 8));
#pragma unroll
        for (int ct = 0; ct < 3; ++ct) {
            bf16x8 bx = *(const bf16x8*)(&Bx[(ct * 16 + lr) * 40 + lq * 8]);
            accR[ct] = __builtin_amdgcn_mfma_f32_16x16x32_bf16(aR, bx, accR[ct], 0, 0, 0);
        }
    }

    // epilogue: GLU + BN + residual
    float bpv[4], bqv[4], scv[4], mnv[4], bev[4], brv[4];
#pragma unroll
    for (int j = 0; j < 4; ++j) {
        int cj = w * 16 + lq * 4 + j;       // 0..63
        bpv[j] = bg[cj]; bqv[j] = bg[64 + cj];
        scv[j] = gam[cj] * rsqrtf(var[cj] + EPSV);
        mnv[j] = mean[cj]; bev[j] = bet[cj]; brv[j] = bres[cj];
    }
#pragma unroll
    for (int ct = 0; ct < 3; ++ct) {
        int col = ct * 16 + lr;
        int n = n0 + col / 12, t = col % 12;
#pragma unroll
        for (int j = 0; j < 4; ++j) {
            int cj = w * 16 + lq * 4 + j;
            float h = (accP[ct][j] + bpv[j]) * sigmoidf_(accQ[ct][j] + bqv[j]);
            float o = (h - mnv[j]) * scv[j] + bev[j] + accR[ct][j] + brv[j];
            out[((size_t)(b * 64 + cj) * NN + n) * 12 + t] = o;
        }
    }
}

extern "C" void kernel_launch(void* const* d_in, const int* in_sizes, int n_in,
                              void* d_out, int out_size, void* d_ws, size_t ws_size,
                              hipStream_t stream)
{
    const float* x   = (const float*)d_in[0];
    const int*   ei  = (const int*)d_in[1];
    const float* ew  = (const float*)d_in[2];
    const float* wg1 = (const float*)d_in[3];
    const float* bg1 = (const float*)d_in[4];
    const float* g1  = (const float*)d_in[5];
    const float* be1 = (const float*)d_in[6];
    const float* m1  = (const float*)d_in[7];
    const float* v1  = (const float*)d_in[8];
    const float* cw  = (const float*)d_in[9];
    const float* cb  = (const float*)d_in[10];
    const float* lng = (const float*)d_in[11];
    const float* lnb = (const float*)d_in[12];
    const float* wg2 = (const float*)d_in[13];
    const float* bg2 = (const float*)d_in[14];
    const float* g2  = (const float*)d_in[15];
    const float* be2 = (const float*)d_in[16];
    const float* m2  = (const float*)d_in[17];
    const float* v2  = (const float*)d_in[18];
    const float* wr  = (const float*)d_in[19];
    const float* br  = (const float*)d_in[20];

    char* w = (char*)d_ws;
    short* wbf1  = (short*)w;  w += 12288 * 2;
    short* wbf2  = (short*)w;  w += 24576 * 2;
    short* wrbf  = (short*)w;  w += 2048 * 2;
    float* h1    = (float*)w;  w += (size_t)BT * NN * 64 * 4;   // 245.76 MB
    float* deg   = (float*)w;  w += NN * 4;
    int*   cnt   = (int*)w;    w += NN * 4;
    int*   offs  = (int*)w;    w += (NN + 1) * 4;
    int*   cursor= (int*)w;    w += NN * 4;
    float* nrm   = (float*)w;  w += EE * 4;
    int*   csrs  = (int*)w;    w += EE * 4;
    float* csrw  = (float*)w;  w += EE * 4;
    float* G = (float*)d_out;   // reuse output buffer as Cheb scratch field

    hipMemsetAsync(deg, 0, NN * 4 * 2, stream);   // deg + cnt

    k_deg<<<625, 256, 0, stream>>>(ei, ew, deg);
    k_dinv<<<40, 256, 0, stream>>>(deg);
    k_norm_cnt<<<625, 256, 0, stream>>>(ei, ew, deg, nrm, cnt);
    k_scan<<<1, 1024, 0, stream>>>(cnt, offs, cursor);
    k_fill<<<625, 256, 0, stream>>>(ei, nrm, cursor, csrs, csrw);
    k_cvt_w<<<96, 256, 0, stream>>>(wg1, wg2, wr, wbf1, wbf2, wrbf);

    k_tconv1_mfma<<<BB * 2500, 256, 0, stream>>>(x, wbf1, bg1, g1, be1, m1, v1, h1);
    k_gather1<<<BT * (NN / 4), 256, 0, stream>>>(h1, offs, csrs, csrw, G);
    k_cheb_mm<<<BT * 250, 256, 0, stream>>>(h1, G, cw, cb);
    k_gather2_ln<<<BT * (NN / 4), 256, 0, stream>>>(h1, G, offs, csrs, csrw, lng, lnb);
    k_tconv2_mfma<<<BB * 2500, 256, 0, stream>>>(h1, x, wbf2, wrbf, bg2, g2, be2, m2, v2, br,
                                                 (float*)d_out);
}

// Round 3
// 2847.124 us; speedup vs baseline: 1.7554x; 1.1012x over previous
//
#include <hip/hip_runtime.h>
#include <math.h>

#define BB 8
#define CIN 32
#define NN 10000
#define TTT 12
#define EE 160000
#define CSP 64
#define BT (BB*TTT)   // 96
#define EPSV 1e-5f

typedef __attribute__((ext_vector_type(8))) short bf16x8;
typedef __attribute__((ext_vector_type(4))) float f32x4;

static __device__ __forceinline__ float sigmoidf_(float v) {
    return __builtin_amdgcn_rcpf(1.f + __expf(-v));
}

static __device__ __forceinline__ short f2bf(float v) {
    unsigned u = __float_as_uint(v);
    u = (u + 0x7fffu + ((u >> 16) & 1u)) >> 16;
    return (short)u;
}
static __device__ __forceinline__ float bf2f(unsigned u16) {
    return __uint_as_float(u16 << 16);
}

// ---------------- graph preprocessing ----------------
__global__ void k_deg(const int* __restrict__ ei, const float* __restrict__ ew,
                      float* __restrict__ deg) {
    int e = blockIdx.x * 256 + threadIdx.x;
    if (e < EE) atomicAdd(&deg[ei[e]], ew[e]);
}

__global__ void k_dinv(float* __restrict__ deg) {
    int n = blockIdx.x * 256 + threadIdx.x;
    if (n < NN) { float d = deg[n]; deg[n] = d > 0.f ? rsqrtf(d) : 0.f; }
}

__global__ void k_norm_cnt(const int* __restrict__ ei, const float* __restrict__ ew,
                           const float* __restrict__ dinv, float* __restrict__ nrm,
                           int* __restrict__ cnt) {
    int e = blockIdx.x * 256 + threadIdx.x;
    if (e < EE) {
        int r = ei[e], c = ei[EE + e];
        nrm[e] = -ew[e] * dinv[r] * dinv[c];
        atomicAdd(&cnt[c], 1);
    }
}

__global__ void k_scan(const int* __restrict__ cnt, int* __restrict__ offs,
                       int* __restrict__ cursor) {
    __shared__ int sh[1024];
    int tid = threadIdx.x;
    int running = 0;
    for (int base = 0; base < NN; base += 1024) {
        int i = base + tid;
        int v = (i < NN) ? cnt[i] : 0;
        sh[tid] = v;
        __syncthreads();
        for (int off = 1; off < 1024; off <<= 1) {
            int t = (tid >= off) ? sh[tid - off] : 0;
            __syncthreads();
            sh[tid] += t;
            __syncthreads();
        }
        int incl = sh[tid];
        if (i < NN) { offs[i] = running + incl - v; cursor[i] = running + incl - v; }
        int ct = sh[1023];
        __syncthreads();
        running += ct;
    }
    if (tid == 0) offs[NN] = running;
}

__global__ void k_fill(const int* __restrict__ ei, const float* __restrict__ nrm,
                       int* __restrict__ cursor, int* __restrict__ csr_src,
                       float* __restrict__ csr_w) {
    int e = blockIdx.x * 256 + threadIdx.x;
    if (e < EE) {
        int cdst = ei[EE + e];
        int p = atomicAdd(&cursor[cdst], 1);
        csr_src[p] = ei[e];
        csr_w[p] = nrm[e];
    }
}

// ---------------- weight conversion to bf16 ----------------
__global__ void k_cvt_w(const float* __restrict__ wg1, const float* __restrict__ wg2,
                        const float* __restrict__ wr, const float* __restrict__ cwf,
                        short* __restrict__ o1, short* __restrict__ o2,
                        short* __restrict__ o3, short* __restrict__ wt02,
                        short* __restrict__ wt1, short* __restrict__ wt2) {
    int i = blockIdx.x * 256 + threadIdx.x;
    if (i < 12288) o1[i] = f2bf(wg1[i]);
    if (i < 24576) o2[i] = f2bf(wg2[i]);
    if (i < 2048)  o3[i] = f2bf(wr[i]);
    if (i < 4096) {
        int cout = i >> 6, cin = i & 63;
        float w0 = cwf[cin * 64 + cout];
        float w1 = cwf[4096 + cin * 64 + cout];
        float w2 = cwf[8192 + cin * 64 + cout];
        wt02[i] = f2bf(w0 - w2);
        wt1[i]  = f2bf(w1);
        wt2[i]  = f2bf(w2);
    }
}

// ---------------- temporal block 1 (MFMA) -> h1 bf16 ----------------
__global__ __launch_bounds__(256, 4) void k_tconv1_mfma(
    const float* __restrict__ x, const short* __restrict__ wbf,
    const float* __restrict__ bg, const float* __restrict__ gam,
    const float* __restrict__ bet, const float* __restrict__ mean,
    const float* __restrict__ var, ushort* __restrict__ h1)
{
    __shared__ short Btl[3 * 48 * 40];
    int bi = blockIdx.x;
    int b = bi / 2500;
    int n0 = (bi % 2500) * 4;
    int tid = threadIdx.x;

    for (int j = tid; j < 384; j += 256) {
        int ci = j / 12, r = j - ci * 12;
        const float* xp = x + ((size_t)(b * CIN + ci) * NN + n0) * 12 + r * 4;
        float4 v = *(const float4*)xp;
        float vv[4] = {v.x, v.y, v.z, v.w};
#pragma unroll
        for (int e = 0; e < 4; ++e) {
            int at = r * 4 + e;
            int n = at / 12, t = at - n * 12;
            short bv = f2bf(vv[e]);
#pragma unroll
            for (int kk = 0; kk < 3; ++kk) {
                int tp = t + 1 - kk;
                if (tp >= 0 && tp < 12) {
                    int K = ci * 3 + kk;
                    Btl[((K >> 5) * 48 + n * 12 + tp) * 40 + (K & 31)] = bv;
                }
            }
            if (t == 0)  { int K = ci * 3;     Btl[((K >> 5) * 48 + n * 12) * 40 + (K & 31)] = 0; }
            if (t == 11) { int K = ci * 3 + 2; Btl[((K >> 5) * 48 + n * 12 + 11) * 40 + (K & 31)] = 0; }
        }
    }
    __syncthreads();

    int w = tid >> 6, l = tid & 63, lr = l & 15, lq = l >> 4;
    f32x4 aP[3], aQ[3];
#pragma unroll
    for (int m = 0; m < 3; ++m) { aP[m] = (f32x4){0,0,0,0}; aQ[m] = (f32x4){0,0,0,0}; }

#pragma unroll
    for (int ks = 0; ks < 3; ++ks) {
        bf16x8 wp = *(const bf16x8*)(wbf + ((w * 16 + lr) * 96 + ks * 32 + lq * 8));
        bf16x8 wq = *(const bf16x8*)(wbf + ((64 + w * 16 + lr) * 96 + ks * 32 + lq * 8));
#pragma unroll
        for (int mt = 0; mt < 3; ++mt) {
            bf16x8 im = *(const bf16x8*)(&Btl[(ks * 48 + mt * 16 + lr) * 40 + lq * 8]);
            aP[mt] = __builtin_amdgcn_mfma_f32_16x16x32_bf16(im, wp, aP[mt], 0, 0, 0);
            aQ[mt] = __builtin_amdgcn_mfma_f32_16x16x32_bf16(im, wq, aQ[mt], 0, 0, 0);
        }
    }

    int c = w * 16 + lr;
    float bp = bg[c], bq = bg[64 + c];
    float sc = gam[c] * rsqrtf(var[c] + EPSV);
    float mn = mean[c], be = bet[c];
#pragma unroll
    for (int mt = 0; mt < 3; ++mt) {
#pragma unroll
        for (int j = 0; j < 4; ++j) {
            int row = mt * 16 + lq * 4 + j;
            int n = n0 + row / 12, t = row % 12;
            float h = (aP[mt][j] + bp) * sigmoidf_(aQ[mt][j] + bq);
            h1[((size_t)(b * TTT + t) * NN + n) * 64 + c] = (ushort)f2bf((h - mn) * sc + be);
        }
    }
}

// ---------------- fused gather1 + Cheb einsum (MFMA) ----------------
// per block: 64 nodes of one snapshot. O = T0@(W0-W2) + G@W1 + b ; U = G@W2
__global__ __launch_bounds__(256) void k_spatial(
    const ushort* __restrict__ h1, const int* __restrict__ offs,
    const int* __restrict__ src, const float* __restrict__ wgt,
    const short* __restrict__ wt02, const short* __restrict__ wt1,
    const short* __restrict__ wt2, const float* __restrict__ cb,
    ushort* __restrict__ O, ushort* __restrict__ U)
{
    __shared__ short Wl[3][64][72];
    __shared__ short Al[64][72];
    __shared__ short Gl[64][72];
    int tid = threadIdx.x;
    int bi = blockIdx.x;
    int bt = bi / 157;
    int n0 = (bi % 157) * 64;

#pragma unroll
    for (int r = 0; r < 2; ++r) {
        int g = tid + r * 256;            // 0..511
        int row = g >> 3, seg = g & 7;
        *(bf16x8*)&Wl[0][row][seg * 8] = *(const bf16x8*)(wt02 + row * 64 + seg * 8);
        *(bf16x8*)&Wl[1][row][seg * 8] = *(const bf16x8*)(wt1  + row * 64 + seg * 8);
        *(bf16x8*)&Wl[2][row][seg * 8] = *(const bf16x8*)(wt2  + row * 64 + seg * 8);
    }

    const ushort* hb = h1 + (size_t)bt * NN * 64;
    int w = tid >> 6, l = tid & 63;
    int nsel = l >> 5, cp = l & 31;

    for (int p = 0; p < 8; ++p) {
        int nl = p * 8 + w * 2 + nsel;
        int n = n0 + nl;
        float acc0 = 0.f, acc1 = 0.f;
        unsigned a_self = 0;
        if (n < NN) {
            a_self = *(const unsigned*)(hb + (size_t)n * 64 + cp * 2);
            int o0 = offs[n], o1 = offs[n + 1];
            for (int i = o0; i < o1; ++i) {
                int s = src[i];
                float ww = wgt[i];
                unsigned pv = *(const unsigned*)(hb + (size_t)s * 64 + cp * 2);
                acc0 = fmaf(ww, bf2f(pv & 0xffffu), acc0);
                acc1 = fmaf(ww, bf2f(pv >> 16), acc1);
            }
        }
        *(unsigned*)&Al[nl][cp * 2] = a_self;
        unsigned gp = ((unsigned)(ushort)f2bf(acc0)) | (((unsigned)(ushort)f2bf(acc1)) << 16);
        *(unsigned*)&Gl[nl][cp * 2] = gp;
    }
    __syncthreads();

    int lr = l & 15, lq = l >> 4;
    bf16x8 af[2], gf[2];
#pragma unroll
    for (int ks = 0; ks < 2; ++ks) {
        af[ks] = *(const bf16x8*)&Al[w * 16 + lr][ks * 32 + lq * 8];
        gf[ks] = *(const bf16x8*)&Gl[w * 16 + lr][ks * 32 + lq * 8];
    }
    f32x4 ao[4], au[4];
#pragma unroll
    for (int ct = 0; ct < 4; ++ct) { ao[ct] = (f32x4){0,0,0,0}; au[ct] = (f32x4){0,0,0,0}; }
#pragma unroll
    for (int ct = 0; ct < 4; ++ct) {
#pragma unroll
        for (int ks = 0; ks < 2; ++ks) {
            bf16x8 b02 = *(const bf16x8*)&Wl[0][ct * 16 + lr][ks * 32 + lq * 8];
            bf16x8 b1  = *(const bf16x8*)&Wl[1][ct * 16 + lr][ks * 32 + lq * 8];
            bf16x8 b2  = *(const bf16x8*)&Wl[2][ct * 16 + lr][ks * 32 + lq * 8];
            ao[ct] = __builtin_amdgcn_mfma_f32_16x16x32_bf16(af[ks], b02, ao[ct], 0, 0, 0);
            ao[ct] = __builtin_amdgcn_mfma_f32_16x16x32_bf16(gf[ks], b1,  ao[ct], 0, 0, 0);
            au[ct] = __builtin_amdgcn_mfma_f32_16x16x32_bf16(gf[ks], b2,  au[ct], 0, 0, 0);
        }
    }
    __syncthreads();   // all frag reads done before overwriting Al/Gl

#pragma unroll
    for (int ct = 0; ct < 4; ++ct) {
        float bb = cb[ct * 16 + lr];
#pragma unroll
        for (int j = 0; j < 4; ++j) {
            int node = w * 16 + lq * 4 + j;
            Al[node][ct * 16 + lr] = f2bf(ao[ct][j] + bb);
            Gl[node][ct * 16 + lr] = f2bf(au[ct][j]);
        }
    }
    __syncthreads();

    size_t obase = (size_t)bt * NN * 64 + (size_t)n0 * 64;
#pragma unroll
    for (int r = 0; r < 2; ++r) {
        int idx = tid + r * 256;
        int node = idx >> 3, seg = idx & 7;
        if (n0 + node < NN) {
            *(bf16x8*)(O + obase + node * 64 + seg * 8) = *(const bf16x8*)&Al[node][seg * 8];
            *(bf16x8*)(U + obase + node * 64 + seg * 8) = *(const bf16x8*)&Gl[node][seg * 8];
        }
    }
}

// ---------------- gather 2 + LayerNorm + ReLU -> hln bf16 ----------------
__global__ __launch_bounds__(256) void k_gather2_ln(
    const ushort* __restrict__ O, const ushort* __restrict__ U,
    const int* __restrict__ offs, const int* __restrict__ src,
    const float* __restrict__ wgt, const float* __restrict__ lng,
    const float* __restrict__ lnb, ushort* __restrict__ hln)
{
    int bi = blockIdx.x;
    int bt = bi / 1250;
    int ng = (bi % 1250) * 8;
    int tid = threadIdx.x;
    int w = tid >> 6, l = tid & 63;
    int n = ng + w * 2 + (l >> 5);
    int cp = l & 31;
    const ushort* Ub = U + (size_t)bt * NN * 64;
    size_t sidx = (size_t)bt * NN * 64 + (size_t)n * 64 + cp * 2;
    unsigned ov = *(const unsigned*)(O + sidx);
    float acc0 = bf2f(ov & 0xffffu), acc1 = bf2f(ov >> 16);
    int o0 = offs[n], o1 = offs[n + 1];
    for (int i = o0; i < o1; ++i) {
        int s = src[i];
        float ww = 2.f * wgt[i];
        unsigned pv = *(const unsigned*)(Ub + (size_t)s * 64 + cp * 2);
        acc0 = fmaf(ww, bf2f(pv & 0xffffu), acc0);
        acc1 = fmaf(ww, bf2f(pv >> 16), acc1);
    }
    float s1 = acc0 + acc1, s2 = acc0 * acc0 + acc1 * acc1;
#pragma unroll
    for (int m = 16; m >= 1; m >>= 1) {
        s1 += __shfl_xor(s1, m);
        s2 += __shfl_xor(s2, m);
    }
    float mu = s1 * (1.f / 64.f);
    float vr = s2 * (1.f / 64.f) - mu * mu;
    float rstd = rsqrtf(vr + EPSV);
    float2 g = *(const float2*)(lng + cp * 2);
    float2 be = *(const float2*)(lnb + cp * 2);
    float y0 = fmaxf((acc0 - mu) * rstd * g.x + be.x, 0.f);
    float y1 = fmaxf((acc1 - mu) * rstd * g.y + be.y, 0.f);
    unsigned pk = ((unsigned)(ushort)f2bf(y0)) | (((unsigned)(ushort)f2bf(y1)) << 16);
    *(unsigned*)(hln + sidx) = pk;
}

// ---------------- temporal block 2 + residual (MFMA) ----------------
__global__ __launch_bounds__(256, 4) void k_tconv2_mfma(
    const ushort* __restrict__ hln, const float* __restrict__ x,
    const short* __restrict__ wbf, const short* __restrict__ wrbf,
    const float* __restrict__ bg, const float* __restrict__ gam,
    const float* __restrict__ bet, const float* __restrict__ mean,
    const float* __restrict__ var, const float* __restrict__ bres,
    float* __restrict__ out)
{
    __shared__ short Btl[6 * 48 * 40];
    __shared__ short Bx[48 * 40];
    int bi = blockIdx.x;
    int b = bi / 2500;
    int n0 = (bi % 2500) * 4;
    int tid = threadIdx.x;

    {
        int n = tid >> 6, c = tid & 63;
#pragma unroll
        for (int t = 0; t < 12; ++t) {
            short bv = (short)hln[((size_t)(b * TTT + t) * NN + n0 + n) * 64 + c];
#pragma unroll
            for (int kk = 0; kk < 3; ++kk) {
                int tp = t + 1 - kk;
                if (tp >= 0 && tp < 12) {
                    int K = c * 3 + kk;
                    Btl[((K >> 5) * 48 + n * 12 + tp) * 40 + (K & 31)] = bv;
                }
            }
            if (t == 0)  { int K = c * 3;     Btl[((K >> 5) * 48 + n * 12) * 40 + (K & 31)] = 0; }
            if (t == 11) { int K = c * 3 + 2; Btl[((K >> 5) * 48 + n * 12 + 11) * 40 + (K & 31)] = 0; }
        }
    }
    for (int j = tid; j < 384; j += 256) {
        int ci = j / 12, r = j - ci * 12;
        const float* xp = x + ((size_t)(b * CIN + ci) * NN + n0) * 12 + r * 4;
        float4 v = *(const float4*)xp;
        float vv[4] = {v.x, v.y, v.z, v.w};
#pragma unroll
        for (int e = 0; e < 4; ++e) {
            int col = r * 4 + e;
            Bx[col * 40 + ci] = f2bf(vv[e]);
        }
    }
    __syncthreads();

    int w = tid >> 6, l = tid & 63, lr = l & 15, lq = l >> 4;
    f32x4 accP[3], accQ[3], accR[3];
#pragma unroll
    for (int m = 0; m < 3; ++m) {
        accP[m] = (f32x4){0,0,0,0}; accQ[m] = (f32x4){0,0,0,0}; accR[m] = (f32x4){0,0,0,0};
    }

#pragma unroll
    for (int ks = 0; ks < 6; ++ks) {
        bf16x8 aP = *(const bf16x8*)(wbf + ((w * 16 + lr) * 192 + ks * 32 + lq * 8));
        bf16x8 aQ = *(const bf16x8*)(wbf + ((64 + w * 16 + lr) * 192 + ks * 32 + lq * 8));
#pragma unroll
        for (int ct = 0; ct < 3; ++ct) {
            bf16x8 bfr = *(const bf16x8*)(&Btl[(ks * 48 + ct * 16 + lr) * 40 + lq * 8]);
            accP[ct] = __builtin_amdgcn_mfma_f32_16x16x32_bf16(aP, bfr, accP[ct], 0, 0, 0);
            accQ[ct] = __builtin_amdgcn_mfma_f32_16x16x32_bf16(aQ, bfr, accQ[ct], 0, 0, 0);
        }
    }
    {
        bf16x8 aR = *(const bf16x8*)(wrbf + ((w * 16 + lr) * 32 + lq * 8));
#pragma unroll
        for (int ct = 0; ct < 3; ++ct) {
            bf16x8 bx = *(const bf16x8*)(&Bx[(ct * 16 + lr) * 40 + lq * 8]);
            accR[ct] = __builtin_amdgcn_mfma_f32_16x16x32_bf16(aR, bx, accR[ct], 0, 0, 0);
        }
    }

    float bpv[4], bqv[4], scv[4], mnv[4], bev[4], brv[4];
#pragma unroll
    for (int j = 0; j < 4; ++j) {
        int cj = w * 16 + lq * 4 + j;
        bpv[j] = bg[cj]; bqv[j] = bg[64 + cj];
        scv[j] = gam[cj] * rsqrtf(var[cj] + EPSV);
        mnv[j] = mean[cj]; bev[j] = bet[cj]; brv[j] = bres[cj];
    }
#pragma unroll
    for (int ct = 0; ct < 3; ++ct) {
        int col = ct * 16 + lr;
        int n = n0 + col / 12, t = col % 12;
#pragma unroll
        for (int j = 0; j < 4; ++j) {
            int cj = w * 16 + lq * 4 + j;
            float h = (accP[ct][j] + bpv[j]) * sigmoidf_(accQ[ct][j] + bqv[j]);
            float o = (h - mnv[j]) * scv[j] + bev[j] + accR[ct][j] + brv[j];
            out[((size_t)(b * 64 + cj) * NN + n) * 12 + t] = o;
        }
    }
}

extern "C" void kernel_launch(void* const* d_in, const int* in_sizes, int n_in,
                              void* d_out, int out_size, void* d_ws, size_t ws_size,
                              hipStream_t stream)
{
    const float* x   = (const float*)d_in[0];
    const int*   ei  = (const int*)d_in[1];
    const float* ew  = (const float*)d_in[2];
    const float* wg1 = (const float*)d_in[3];
    const float* bg1 = (const float*)d_in[4];
    const float* g1  = (const float*)d_in[5];
    const float* be1 = (const float*)d_in[6];
    const float* m1  = (const float*)d_in[7];
    const float* v1  = (const float*)d_in[8];
    const float* cw  = (const float*)d_in[9];
    const float* cb  = (const float*)d_in[10];
    const float* lng = (const float*)d_in[11];
    const float* lnb = (const float*)d_in[12];
    const float* wg2 = (const float*)d_in[13];
    const float* bg2 = (const float*)d_in[14];
    const float* g2  = (const float*)d_in[15];
    const float* be2 = (const float*)d_in[16];
    const float* m2  = (const float*)d_in[17];
    const float* v2  = (const float*)d_in[18];
    const float* wr  = (const float*)d_in[19];
    const float* br  = (const float*)d_in[20];

    char* w = (char*)d_ws;
    short* wbf1  = (short*)w;  w += 12288 * 2;
    short* wbf2  = (short*)w;  w += 24576 * 2;
    short* wrbf  = (short*)w;  w += 2048 * 2;
    short* wt02  = (short*)w;  w += 4096 * 2;
    short* wt1   = (short*)w;  w += 4096 * 2;
    short* wt2   = (short*)w;  w += 4096 * 2;
    ushort* h1   = (ushort*)w; w += (size_t)BT * NN * 64 * 2;   // 122.88 MB (reused as hln)
    ushort* O    = (ushort*)w; w += (size_t)BT * NN * 64 * 2;   // 122.88 MB
    float* deg   = (float*)w;  w += NN * 4;
    int*   cnt   = (int*)w;    w += NN * 4;
    int*   offs  = (int*)w;    w += (NN + 1) * 4;
    int*   cursor= (int*)w;    w += NN * 4;
    float* nrm   = (float*)w;  w += EE * 4;
    int*   csrs  = (int*)w;    w += EE * 4;
    float* csrw  = (float*)w;  w += EE * 4;
    ushort* U = (ushort*)d_out;   // reuse output buffer as U field (bf16)

    hipMemsetAsync(deg, 0, NN * 4 * 2, stream);   // deg + cnt

    k_deg<<<625, 256, 0, stream>>>(ei, ew, deg);
    k_dinv<<<40, 256, 0, stream>>>(deg);
    k_norm_cnt<<<625, 256, 0, stream>>>(ei, ew, deg, nrm, cnt);
    k_scan<<<1, 1024, 0, stream>>>(cnt, offs, cursor);
    k_fill<<<625, 256, 0, stream>>>(ei, nrm, cursor, csrs, csrw);
    k_cvt_w<<<96, 256, 0, stream>>>(wg1, wg2, wr, cw, wbf1, wbf2, wrbf, wt02, wt1, wt2);

    k_tconv1_mfma<<<BB * 2500, 256, 0, stream>>>(x, wbf1, bg1, g1, be1, m1, v1, h1);
    k_spatial<<<BT * 157, 256, 0, stream>>>(h1, offs, csrs, csrw, wt02, wt1, wt2, cb, O, U);
    k_gather2_ln<<<BT * 1250, 256, 0, stream>>>(O, U, offs, csrs, csrw, lng, lnb, h1);
    k_tconv2_mfma<<<BB * 2500, 256, 0, stream>>>(h1, x, wbf2, wrbf, bg2, g2, be2, m2, v2, br,
                                                 (float*)d_out);
}

// Round 4
// 1263.267 us; speedup vs baseline: 3.9563x; 2.2538x over previous
//
#include <hip/hip_runtime.h>
#include <math.h>

#define BB 8
#define CIN 32
#define NN 10000
#define TTT 12
#define EE 160000
#define CSP 64
#define BT (BB*TTT)   // 96
#define EPSV 1e-5f

typedef __attribute__((ext_vector_type(8))) short bf16x8;
typedef __attribute__((ext_vector_type(4))) float f32x4;

static __device__ __forceinline__ float sigmoidf_(float v) {
    return __builtin_amdgcn_rcpf(1.f + __expf(-v));
}

static __device__ __forceinline__ short f2bf(float v) {
    unsigned u = __float_as_uint(v);
    u = (u + 0x7fffu + ((u >> 16) & 1u)) >> 16;
    return (short)u;
}
static __device__ __forceinline__ float bf2f(unsigned u16) {
    return __uint_as_float(u16 << 16);
}

// ---------------- graph preprocessing ----------------
__global__ void k_deg(const int* __restrict__ ei, const float* __restrict__ ew,
                      float* __restrict__ deg) {
    int e = blockIdx.x * 256 + threadIdx.x;
    if (e < EE) atomicAdd(&deg[ei[e]], ew[e]);
}

__global__ void k_dinv(float* __restrict__ deg) {
    int n = blockIdx.x * 256 + threadIdx.x;
    if (n < NN) { float d = deg[n]; deg[n] = d > 0.f ? rsqrtf(d) : 0.f; }
}

__global__ void k_norm_cnt(const int* __restrict__ ei, const float* __restrict__ ew,
                           const float* __restrict__ dinv, float* __restrict__ nrm,
                           int* __restrict__ cnt) {
    int e = blockIdx.x * 256 + threadIdx.x;
    if (e < EE) {
        int r = ei[e], c = ei[EE + e];
        nrm[e] = -ew[e] * dinv[r] * dinv[c];
        atomicAdd(&cnt[c], 1);
    }
}

__global__ void k_scan(const int* __restrict__ cnt, int* __restrict__ offs,
                       int* __restrict__ cursor) {
    __shared__ int sh[1024];
    int tid = threadIdx.x;
    int running = 0;
    for (int base = 0; base < NN; base += 1024) {
        int i = base + tid;
        int v = (i < NN) ? cnt[i] : 0;
        sh[tid] = v;
        __syncthreads();
        for (int off = 1; off < 1024; off <<= 1) {
            int t = (tid >= off) ? sh[tid - off] : 0;
            __syncthreads();
            sh[tid] += t;
            __syncthreads();
        }
        int incl = sh[tid];
        if (i < NN) { offs[i] = running + incl - v; cursor[i] = running + incl - v; }
        int ct = sh[1023];
        __syncthreads();
        running += ct;
    }
    if (tid == 0) offs[NN] = running;
}

__global__ void k_fill(const int* __restrict__ ei, const float* __restrict__ nrm,
                       int* __restrict__ cursor, int* __restrict__ csr_src,
                       float* __restrict__ csr_w) {
    int e = blockIdx.x * 256 + threadIdx.x;
    if (e < EE) {
        int cdst = ei[EE + e];
        int p = atomicAdd(&cursor[cdst], 1);
        csr_src[p] = ei[e];
        csr_w[p] = nrm[e];
    }
}

// ---------------- weight conversion to bf16 ----------------
__global__ void k_cvt_w(const float* __restrict__ wg1, const float* __restrict__ wg2,
                        const float* __restrict__ wr, const float* __restrict__ cwf,
                        short* __restrict__ o1, short* __restrict__ o2,
                        short* __restrict__ o3, short* __restrict__ wt02,
                        short* __restrict__ wt1, short* __restrict__ wt2) {
    int i = blockIdx.x * 256 + threadIdx.x;
    if (i < 12288) o1[i] = f2bf(wg1[i]);
    if (i < 24576) o2[i] = f2bf(wg2[i]);
    if (i < 2048)  o3[i] = f2bf(wr[i]);
    if (i < 4096) {
        int cout = i >> 6, cin = i & 63;
        float w0 = cwf[cin * 64 + cout];
        float w1 = cwf[4096 + cin * 64 + cout];
        float w2 = cwf[8192 + cin * 64 + cout];
        wt02[i] = f2bf(w0 - w2);
        wt1[i]  = f2bf(w1);
        wt2[i]  = f2bf(w2);
    }
}

// ---------------- temporal block 1 (MFMA) -> h1 bf16 ----------------
__global__ __launch_bounds__(256, 4) void k_tconv1_mfma(
    const float* __restrict__ x, const short* __restrict__ wbf,
    const float* __restrict__ bg, const float* __restrict__ gam,
    const float* __restrict__ bet, const float* __restrict__ mean,
    const float* __restrict__ var, ushort* __restrict__ h1)
{
    __shared__ short Btl[3 * 48 * 40];
    int bi = blockIdx.x;
    int b = bi / 2500;
    int n0 = (bi % 2500) * 4;
    int tid = threadIdx.x;

    for (int j = tid; j < 384; j += 256) {
        int ci = j / 12, r = j - ci * 12;
        const float* xp = x + ((size_t)(b * CIN + ci) * NN + n0) * 12 + r * 4;
        float4 v = *(const float4*)xp;
        float vv[4] = {v.x, v.y, v.z, v.w};
#pragma unroll
        for (int e = 0; e < 4; ++e) {
            int at = r * 4 + e;
            int n = at / 12, t = at - n * 12;
            short bv = f2bf(vv[e]);
#pragma unroll
            for (int kk = 0; kk < 3; ++kk) {
                int tp = t + 1 - kk;
                if (tp >= 0 && tp < 12) {
                    int K = ci * 3 + kk;
                    Btl[((K >> 5) * 48 + n * 12 + tp) * 40 + (K & 31)] = bv;
                }
            }
            if (t == 0)  { int K = ci * 3;     Btl[((K >> 5) * 48 + n * 12) * 40 + (K & 31)] = 0; }
            if (t == 11) { int K = ci * 3 + 2; Btl[((K >> 5) * 48 + n * 12 + 11) * 40 + (K & 31)] = 0; }
        }
    }
    __syncthreads();

    int w = tid >> 6, l = tid & 63, lr = l & 15, lq = l >> 4;
    f32x4 aP[3], aQ[3];
#pragma unroll
    for (int m = 0; m < 3; ++m) { aP[m] = (f32x4){0,0,0,0}; aQ[m] = (f32x4){0,0,0,0}; }

#pragma unroll
    for (int ks = 0; ks < 3; ++ks) {
        bf16x8 wp = *(const bf16x8*)(wbf + ((w * 16 + lr) * 96 + ks * 32 + lq * 8));
        bf16x8 wq = *(const bf16x8*)(wbf + ((64 + w * 16 + lr) * 96 + ks * 32 + lq * 8));
#pragma unroll
        for (int mt = 0; mt < 3; ++mt) {
            bf16x8 im = *(const bf16x8*)(&Btl[(ks * 48 + mt * 16 + lr) * 40 + lq * 8]);
            aP[mt] = __builtin_amdgcn_mfma_f32_16x16x32_bf16(im, wp, aP[mt], 0, 0, 0);
            aQ[mt] = __builtin_amdgcn_mfma_f32_16x16x32_bf16(im, wq, aQ[mt], 0, 0, 0);
        }
    }

    int c = w * 16 + lr;
    float bp = bg[c], bq = bg[64 + c];
    float sc = gam[c] * rsqrtf(var[c] + EPSV);
    float mn = mean[c], be = bet[c];
#pragma unroll
    for (int mt = 0; mt < 3; ++mt) {
#pragma unroll
        for (int j = 0; j < 4; ++j) {
            int row = mt * 16 + lq * 4 + j;
            int n = n0 + row / 12, t = row % 12;
            float h = (aP[mt][j] + bp) * sigmoidf_(aQ[mt][j] + bq);
            h1[((size_t)(b * TTT + t) * NN + n) * 64 + c] = (ushort)f2bf((h - mn) * sc + be);
        }
    }
}

// ---------------- fused gather1 + Cheb einsum (MFMA), XCD-pinned ----------------
// grid = 15072 = 8 xcd * 12 snapshots * 157 chunks
__global__ __launch_bounds__(256, 6) void k_spatial(
    const ushort* __restrict__ h1, const int* __restrict__ offs,
    const int* __restrict__ src, const float* __restrict__ wgt,
    const short* __restrict__ wt02, const short* __restrict__ wt1,
    const short* __restrict__ wt2, const float* __restrict__ cb,
    ushort* __restrict__ O, ushort* __restrict__ U)
{
    __shared__ short Al[64][72];
    __shared__ short Gl[64][72];
    int tid = threadIdx.x;
    int bi = blockIdx.x;
    int xcd = bi & 7, j = bi >> 3;          // XCD-pinned snapshot schedule
    int bt = xcd * 12 + j / 157;
    int n0 = (j % 157) * 64;

    const ushort* hb = h1 + (size_t)bt * NN * 64;
    int w = tid >> 6, l = tid & 63;
    int nsel = l >> 5, cp = l & 31;

    for (int p = 0; p < 8; ++p) {
        int nl = p * 8 + w * 2 + nsel;
        int n = n0 + nl;
        float a0 = 0.f, a1 = 0.f, b0 = 0.f, b1 = 0.f;
        float c0 = 0.f, c1 = 0.f, d0 = 0.f, d1 = 0.f;
        unsigned a_self = 0;
        if (n < NN) {
            a_self = *(const unsigned*)(hb + (size_t)n * 64 + cp * 2);
            int o0 = offs[n], o1 = offs[n + 1];
            int i = o0;
            for (; i + 3 < o1; i += 4) {
                int s0 = src[i], s1 = src[i + 1], s2 = src[i + 2], s3 = src[i + 3];
                float w0 = wgt[i], w1 = wgt[i + 1], w2 = wgt[i + 2], w3 = wgt[i + 3];
                unsigned p0 = *(const unsigned*)(hb + (size_t)s0 * 64 + cp * 2);
                unsigned p1 = *(const unsigned*)(hb + (size_t)s1 * 64 + cp * 2);
                unsigned p2 = *(const unsigned*)(hb + (size_t)s2 * 64 + cp * 2);
                unsigned p3 = *(const unsigned*)(hb + (size_t)s3 * 64 + cp * 2);
                a0 = fmaf(w0, bf2f(p0 & 0xffffu), a0); a1 = fmaf(w0, bf2f(p0 >> 16), a1);
                b0 = fmaf(w1, bf2f(p1 & 0xffffu), b0); b1 = fmaf(w1, bf2f(p1 >> 16), b1);
                c0 = fmaf(w2, bf2f(p2 & 0xffffu), c0); c1 = fmaf(w2, bf2f(p2 >> 16), c1);
                d0 = fmaf(w3, bf2f(p3 & 0xffffu), d0); d1 = fmaf(w3, bf2f(p3 >> 16), d1);
            }
            for (; i < o1; ++i) {
                int s = src[i];
                float ww = wgt[i];
                unsigned pv = *(const unsigned*)(hb + (size_t)s * 64 + cp * 2);
                a0 = fmaf(ww, bf2f(pv & 0xffffu), a0);
                a1 = fmaf(ww, bf2f(pv >> 16), a1);
            }
        }
        float acc0 = (a0 + b0) + (c0 + d0);
        float acc1 = (a1 + b1) + (c1 + d1);
        *(unsigned*)&Al[nl][cp * 2] = a_self;
        unsigned gp = ((unsigned)(ushort)f2bf(acc0)) | (((unsigned)(ushort)f2bf(acc1)) << 16);
        *(unsigned*)&Gl[nl][cp * 2] = gp;
    }
    __syncthreads();

    int lr = l & 15, lq = l >> 4;
    bf16x8 af[2], gf[2];
#pragma unroll
    for (int ks = 0; ks < 2; ++ks) {
        af[ks] = *(const bf16x8*)&Al[w * 16 + lr][ks * 32 + lq * 8];
        gf[ks] = *(const bf16x8*)&Gl[w * 16 + lr][ks * 32 + lq * 8];
    }
    f32x4 ao[4], au[4];
#pragma unroll
    for (int ct = 0; ct < 4; ++ct) { ao[ct] = (f32x4){0,0,0,0}; au[ct] = (f32x4){0,0,0,0}; }
#pragma unroll
    for (int ct = 0; ct < 4; ++ct) {
#pragma unroll
        for (int ks = 0; ks < 2; ++ks) {
            int woff = (ct * 16 + lr) * 64 + ks * 32 + lq * 8;
            bf16x8 b02 = *(const bf16x8*)(wt02 + woff);
            bf16x8 b1  = *(const bf16x8*)(wt1 + woff);
            bf16x8 b2  = *(const bf16x8*)(wt2 + woff);
            ao[ct] = __builtin_amdgcn_mfma_f32_16x16x32_bf16(af[ks], b02, ao[ct], 0, 0, 0);
            ao[ct] = __builtin_amdgcn_mfma_f32_16x16x32_bf16(gf[ks], b1,  ao[ct], 0, 0, 0);
            au[ct] = __builtin_amdgcn_mfma_f32_16x16x32_bf16(gf[ks], b2,  au[ct], 0, 0, 0);
        }
    }
    __syncthreads();   // all frag reads done before overwriting Al/Gl

#pragma unroll
    for (int ct = 0; ct < 4; ++ct) {
        float bb = cb[ct * 16 + lr];
#pragma unroll
        for (int j2 = 0; j2 < 4; ++j2) {
            int node = w * 16 + lq * 4 + j2;
            Al[node][ct * 16 + lr] = f2bf(ao[ct][j2] + bb);
            Gl[node][ct * 16 + lr] = f2bf(au[ct][j2]);
        }
    }
    __syncthreads();

    size_t obase = (size_t)bt * NN * 64 + (size_t)n0 * 64;
#pragma unroll
    for (int r = 0; r < 2; ++r) {
        int idx = tid + r * 256;
        int node = idx >> 3, seg = idx & 7;
        if (n0 + node < NN) {
            *(bf16x8*)(O + obase + node * 64 + seg * 8) = *(const bf16x8*)&Al[node][seg * 8];
            *(bf16x8*)(U + obase + node * 64 + seg * 8) = *(const bf16x8*)&Gl[node][seg * 8];
        }
    }
}

// ---------------- gather 2 + LayerNorm + ReLU -> hln bf16, XCD-pinned ----------------
// grid = 120000 = 8 xcd * 12 snapshots * 1250 chunks
__global__ __launch_bounds__(256, 8) void k_gather2_ln(
    const ushort* __restrict__ O, const ushort* __restrict__ U,
    const int* __restrict__ offs, const int* __restrict__ src,
    const float* __restrict__ wgt, const float* __restrict__ lng,
    const float* __restrict__ lnb, ushort* __restrict__ hln)
{
    int bi = blockIdx.x;
    int xcd = bi & 7, jj = bi >> 3;
    int bt = xcd * 12 + jj / 1250;
    int ng = (jj % 1250) * 8;
    int tid = threadIdx.x;
    int w = tid >> 6, l = tid & 63;
    int n = ng + w * 2 + (l >> 5);
    int cp = l & 31;
    const ushort* Ub = U + (size_t)bt * NN * 64;
    size_t sidx = (size_t)bt * NN * 64 + (size_t)n * 64 + cp * 2;
    unsigned ov = *(const unsigned*)(O + sidx);
    float a0 = bf2f(ov & 0xffffu), a1 = bf2f(ov >> 16);
    float b0 = 0.f, b1 = 0.f, c0 = 0.f, c1 = 0.f, d0 = 0.f, d1 = 0.f;
    int o0 = offs[n], o1 = offs[n + 1];
    int i = o0;
    for (; i + 3 < o1; i += 4) {
        int s0 = src[i], s1 = src[i + 1], s2 = src[i + 2], s3 = src[i + 3];
        float w0 = 2.f * wgt[i], w1 = 2.f * wgt[i + 1];
        float w2 = 2.f * wgt[i + 2], w3 = 2.f * wgt[i + 3];
        unsigned p0 = *(const unsigned*)(Ub + (size_t)s0 * 64 + cp * 2);
        unsigned p1 = *(const unsigned*)(Ub + (size_t)s1 * 64 + cp * 2);
        unsigned p2 = *(const unsigned*)(Ub + (size_t)s2 * 64 + cp * 2);
        unsigned p3 = *(const unsigned*)(Ub + (size_t)s3 * 64 + cp * 2);
        a0 = fmaf(w0, bf2f(p0 & 0xffffu), a0); a1 = fmaf(w0, bf2f(p0 >> 16), a1);
        b0 = fmaf(w1, bf2f(p1 & 0xffffu), b0); b1 = fmaf(w1, bf2f(p1 >> 16), b1);
        c0 = fmaf(w2, bf2f(p2 & 0xffffu), c0); c1 = fmaf(w2, bf2f(p2 >> 16), c1);
        d0 = fmaf(w3, bf2f(p3 & 0xffffu), d0); d1 = fmaf(w3, bf2f(p3 >> 16), d1);
    }
    for (; i < o1; ++i) {
        int s = src[i];
        float ww = 2.f * wgt[i];
        unsigned pv = *(const unsigned*)(Ub + (size_t)s * 64 + cp * 2);
        a0 = fmaf(ww, bf2f(pv & 0xffffu), a0);
        a1 = fmaf(ww, bf2f(pv >> 16), a1);
    }
    float acc0 = (a0 + b0) + (c0 + d0);
    float acc1 = (a1 + b1) + (c1 + d1);
    float s1 = acc0 + acc1, s2 = acc0 * acc0 + acc1 * acc1;
#pragma unroll
    for (int m = 16; m >= 1; m >>= 1) {
        s1 += __shfl_xor(s1, m);
        s2 += __shfl_xor(s2, m);
    }
    float mu = s1 * (1.f / 64.f);
    float vr = s2 * (1.f / 64.f) - mu * mu;
    float rstd = rsqrtf(vr + EPSV);
    float2 g = *(const float2*)(lng + cp * 2);
    float2 be = *(const float2*)(lnb + cp * 2);
    float y0 = fmaxf((acc0 - mu) * rstd * g.x + be.x, 0.f);
    float y1 = fmaxf((acc1 - mu) * rstd * g.y + be.y, 0.f);
    unsigned pk = ((unsigned)(ushort)f2bf(y0)) | (((unsigned)(ushort)f2bf(y1)) << 16);
    *(unsigned*)(hln + sidx) = pk;
}

// ---------------- temporal block 2 + residual (MFMA) ----------------
__global__ __launch_bounds__(256, 4) void k_tconv2_mfma(
    const ushort* __restrict__ hln, const float* __restrict__ x,
    const short* __restrict__ wbf, const short* __restrict__ wrbf,
    const float* __restrict__ bg, const float* __restrict__ gam,
    const float* __restrict__ bet, const float* __restrict__ mean,
    const float* __restrict__ var, const float* __restrict__ bres,
    float* __restrict__ out)
{
    __shared__ short Btl[6 * 48 * 40];
    __shared__ short Bx[48 * 40];
    int bi = blockIdx.x;
    int b = bi / 2500;
    int n0 = (bi % 2500) * 4;
    int tid = threadIdx.x;

    {
        int n = tid >> 6, c = tid & 63;
#pragma unroll
        for (int t = 0; t < 12; ++t) {
            short bv = (short)hln[((size_t)(b * TTT + t) * NN + n0 + n) * 64 + c];
#pragma unroll
            for (int kk = 0; kk < 3; ++kk) {
                int tp = t + 1 - kk;
                if (tp >= 0 && tp < 12) {
                    int K = c * 3 + kk;
                    Btl[((K >> 5) * 48 + n * 12 + tp) * 40 + (K & 31)] = bv;
                }
            }
            if (t == 0)  { int K = c * 3;     Btl[((K >> 5) * 48 + n * 12) * 40 + (K & 31)] = 0; }
            if (t == 11) { int K = c * 3 + 2; Btl[((K >> 5) * 48 + n * 12 + 11) * 40 + (K & 31)] = 0; }
        }
    }
    for (int j = tid; j < 384; j += 256) {
        int ci = j / 12, r = j - ci * 12;
        const float* xp = x + ((size_t)(b * CIN + ci) * NN + n0) * 12 + r * 4;
        float4 v = *(const float4*)xp;
        float vv[4] = {v.x, v.y, v.z, v.w};
#pragma unroll
        for (int e = 0; e < 4; ++e) {
            int col = r * 4 + e;
            Bx[col * 40 + ci] = f2bf(vv[e]);
        }
    }
    __syncthreads();

    int w = tid >> 6, l = tid & 63, lr = l & 15, lq = l >> 4;
    f32x4 accP[3], accQ[3], accR[3];
#pragma unroll
    for (int m = 0; m < 3; ++m) {
        accP[m] = (f32x4){0,0,0,0}; accQ[m] = (f32x4){0,0,0,0}; accR[m] = (f32x4){0,0,0,0};
    }

#pragma unroll
    for (int ks = 0; ks < 6; ++ks) {
        bf16x8 aP = *(const bf16x8*)(wbf + ((w * 16 + lr) * 192 + ks * 32 + lq * 8));
        bf16x8 aQ = *(const bf16x8*)(wbf + ((64 + w * 16 + lr) * 192 + ks * 32 + lq * 8));
#pragma unroll
        for (int ct = 0; ct < 3; ++ct) {
            bf16x8 bfr = *(const bf16x8*)(&Btl[(ks * 48 + ct * 16 + lr) * 40 + lq * 8]);
            accP[ct] = __builtin_amdgcn_mfma_f32_16x16x32_bf16(aP, bfr, accP[ct], 0, 0, 0);
            accQ[ct] = __builtin_amdgcn_mfma_f32_16x16x32_bf16(aQ, bfr, accQ[ct], 0, 0, 0);
        }
    }
    {
        bf16x8 aR = *(const bf16x8*)(wrbf + ((w * 16 + lr) * 32 + lq * 8));
#pragma unroll
        for (int ct = 0; ct < 3; ++ct) {
            bf16x8 bx = *(const bf16x8*)(&Bx[(ct * 16 + lr) * 40 + lq * 8]);
            accR[ct] = __builtin_amdgcn_mfma_f32_16x16x32_bf16(aR, bx, accR[ct], 0, 0, 0);
        }
    }

    float bpv[4], bqv[4], scv[4], mnv[4], bev[4], brv[4];
#pragma unroll
    for (int j = 0; j < 4; ++j) {
        int cj = w * 16 + lq * 4 + j;
        bpv[j] = bg[cj]; bqv[j] = bg[64 + cj];
        scv[j] = gam[cj] * rsqrtf(var[cj] + EPSV);
        mnv[j] = mean[cj]; bev[j] = bet[cj]; brv[j] = bres[cj];
    }
#pragma unroll
    for (int ct = 0; ct < 3; ++ct) {
        int col = ct * 16 + lr;
        int n = n0 + col / 12, t = col % 12;
#pragma unroll
        for (int j = 0; j < 4; ++j) {
            int cj = w * 16 + lq * 4 + j;
            float h = (accP[ct][j] + bpv[j]) * sigmoidf_(accQ[ct][j] + bqv[j]);
            float o = (h - mnv[j]) * scv[j] + bev[j] + accR[ct][j] + brv[j];
            out[((size_t)(b * 64 + cj) * NN + n) * 12 + t] = o;
        }
    }
}

extern "C" void kernel_launch(void* const* d_in, const int* in_sizes, int n_in,
                              void* d_out, int out_size, void* d_ws, size_t ws_size,
                              hipStream_t stream)
{
    const float* x   = (const float*)d_in[0];
    const int*   ei  = (const int*)d_in[1];
    const float* ew  = (const float*)d_in[2];
    const float* wg1 = (const float*)d_in[3];
    const float* bg1 = (const float*)d_in[4];
    const float* g1  = (const float*)d_in[5];
    const float* be1 = (const float*)d_in[6];
    const float* m1  = (const float*)d_in[7];
    const float* v1  = (const float*)d_in[8];
    const float* cw  = (const float*)d_in[9];
    const float* cb  = (const float*)d_in[10];
    const float* lng = (const float*)d_in[11];
    const float* lnb = (const float*)d_in[12];
    const float* wg2 = (const float*)d_in[13];
    const float* bg2 = (const float*)d_in[14];
    const float* g2  = (const float*)d_in[15];
    const float* be2 = (const float*)d_in[16];
    const float* m2  = (const float*)d_in[17];
    const float* v2  = (const float*)d_in[18];
    const float* wr  = (const float*)d_in[19];
    const float* br  = (const float*)d_in[20];

    char* w = (char*)d_ws;
    short* wbf1  = (short*)w;  w += 12288 * 2;
    short* wbf2  = (short*)w;  w += 24576 * 2;
    short* wrbf  = (short*)w;  w += 2048 * 2;
    short* wt02  = (short*)w;  w += 4096 * 2;
    short* wt1   = (short*)w;  w += 4096 * 2;
    short* wt2   = (short*)w;  w += 4096 * 2;
    ushort* h1   = (ushort*)w; w += (size_t)BT * NN * 64 * 2;   // 122.88 MB (reused as hln)
    ushort* O    = (ushort*)w; w += (size_t)BT * NN * 64 * 2;   // 122.88 MB
    float* deg   = (float*)w;  w += NN * 4;
    int*   cnt   = (int*)w;    w += NN * 4;
    int*   offs  = (int*)w;    w += (NN + 1) * 4;
    int*   cursor= (int*)w;    w += NN * 4;
    float* nrm   = (float*)w;  w += EE * 4;
    int*   csrs  = (int*)w;    w += EE * 4;
    float* csrw  = (float*)w;  w += EE * 4;
    ushort* U = (ushort*)d_out;   // reuse output buffer as U field (bf16)

    hipMemsetAsync(deg, 0, NN * 4 * 2, stream);   // deg + cnt

    k_deg<<<625, 256, 0, stream>>>(ei, ew, deg);
    k_dinv<<<40, 256, 0, stream>>>(deg);
    k_norm_cnt<<<625, 256, 0, stream>>>(ei, ew, deg, nrm, cnt);
    k_scan<<<1, 1024, 0, stream>>>(cnt, offs, cursor);
    k_fill<<<625, 256, 0, stream>>>(ei, nrm, cursor, csrs, csrw);
    k_cvt_w<<<96, 256, 0, stream>>>(wg1, wg2, wr, cw, wbf1, wbf2, wrbf, wt02, wt1, wt2);

    k_tconv1_mfma<<<BB * 2500, 256, 0, stream>>>(x, wbf1, bg1, g1, be1, m1, v1, h1);
    k_spatial<<<BT * 157, 256, 0, stream>>>(h1, offs, csrs, csrw, wt02, wt1, wt2, cb, O, U);
    k_gather2_ln<<<BT * 1250, 256, 0, stream>>>(O, U, offs, csrs, csrw, lng, lnb, h1);
    k_tconv2_mfma<<<BB * 2500, 256, 0, stream>>>(h1, x, wbf2, wrbf, bg2, g2, be2, m2, v2, br,
                                                 (float*)d_out);
}

// Round 5
// 1161.705 us; speedup vs baseline: 4.3021x; 1.0874x over previous
//
#include <hip/hip_runtime.h>
#include <math.h>

#define BB 8
#define CIN 32
#define NN 10000
#define TTT 12
#define EE 160000
#define CSP 64
#define BT (BB*TTT)   // 96
#define EPSV 1e-5f

typedef __attribute__((ext_vector_type(8))) short bf16x8;
typedef __attribute__((ext_vector_type(4))) float f32x4;

static __device__ __forceinline__ float sigmoidf_(float v) {
    return __builtin_amdgcn_rcpf(1.f + __expf(-v));
}

static __device__ __forceinline__ short f2bf(float v) {
    unsigned u = __float_as_uint(v);
    u = (u + 0x7fffu + ((u >> 16) & 1u)) >> 16;
    return (short)u;
}
static __device__ __forceinline__ float bf2f(unsigned u16) {
    return __uint_as_float(u16 << 16);
}
static __device__ __forceinline__ float lo16f(unsigned u) {
    return __uint_as_float(u << 16);
}
static __device__ __forceinline__ float hi16f(unsigned u) {
    return __uint_as_float(u & 0xffff0000u);
}
static __device__ __forceinline__ unsigned packbf(float a, float b) {
    return ((unsigned)(ushort)f2bf(a)) | (((unsigned)(ushort)f2bf(b)) << 16);
}

// ---------------- graph preprocessing ----------------
__global__ void k_deg(const int* __restrict__ ei, const float* __restrict__ ew,
                      float* __restrict__ deg) {
    int e = blockIdx.x * 256 + threadIdx.x;
    if (e < EE) atomicAdd(&deg[ei[e]], ew[e]);
}

__global__ void k_dinv(float* __restrict__ deg) {
    int n = blockIdx.x * 256 + threadIdx.x;
    if (n < NN) { float d = deg[n]; deg[n] = d > 0.f ? rsqrtf(d) : 0.f; }
}

__global__ void k_norm_cnt(const int* __restrict__ ei, const float* __restrict__ ew,
                           const float* __restrict__ dinv, float* __restrict__ nrm,
                           int* __restrict__ cnt) {
    int e = blockIdx.x * 256 + threadIdx.x;
    if (e < EE) {
        int r = ei[e], c = ei[EE + e];
        nrm[e] = -ew[e] * dinv[r] * dinv[c];
        atomicAdd(&cnt[c], 1);
    }
}

__global__ void k_scan(const int* __restrict__ cnt, int* __restrict__ offs,
                       int* __restrict__ cursor) {
    __shared__ int sh[1024];
    int tid = threadIdx.x;
    int running = 0;
    for (int base = 0; base < NN; base += 1024) {
        int i = base + tid;
        int v = (i < NN) ? cnt[i] : 0;
        sh[tid] = v;
        __syncthreads();
        for (int off = 1; off < 1024; off <<= 1) {
            int t = (tid >= off) ? sh[tid - off] : 0;
            __syncthreads();
            sh[tid] += t;
            __syncthreads();
        }
        int incl = sh[tid];
        if (i < NN) { offs[i] = running + incl - v; cursor[i] = running + incl - v; }
        int ct = sh[1023];
        __syncthreads();
        running += ct;
    }
    if (tid == 0) offs[NN] = running;
}

__global__ void k_fill(const int* __restrict__ ei, const float* __restrict__ nrm,
                       int* __restrict__ cursor, int2* __restrict__ csr) {
    int e = blockIdx.x * 256 + threadIdx.x;
    if (e < EE) {
        int cdst = ei[EE + e];
        int p = atomicAdd(&cursor[cdst], 1);
        csr[p] = make_int2(ei[e], __float_as_int(nrm[e]));
    }
}

// ---------------- weight conversion to bf16 ----------------
__global__ void k_cvt_w(const float* __restrict__ wg1, const float* __restrict__ wg2,
                        const float* __restrict__ wr, const float* __restrict__ cwf,
                        short* __restrict__ o1, short* __restrict__ o2,
                        short* __restrict__ o3, short* __restrict__ wt02,
                        short* __restrict__ wt1, short* __restrict__ wt2) {
    int i = blockIdx.x * 256 + threadIdx.x;
    if (i < 12288) o1[i] = f2bf(wg1[i]);
    if (i < 24576) o2[i] = f2bf(wg2[i]);
    if (i < 2048)  o3[i] = f2bf(wr[i]);
    if (i < 4096) {
        int cout = i >> 6, cin = i & 63;
        float w0 = cwf[cin * 64 + cout];
        float w1 = cwf[4096 + cin * 64 + cout];
        float w2 = cwf[8192 + cin * 64 + cout];
        wt02[i] = f2bf(w0 - w2);
        wt1[i]  = f2bf(w1);
        wt2[i]  = f2bf(w2);
    }
}

// ---------------- temporal block 1 (MFMA) -> h1 bf16 ----------------
__global__ __launch_bounds__(256, 4) void k_tconv1_mfma(
    const float* __restrict__ x, const short* __restrict__ wbf,
    const float* __restrict__ bg, const float* __restrict__ gam,
    const float* __restrict__ bet, const float* __restrict__ mean,
    const float* __restrict__ var, ushort* __restrict__ h1)
{
    __shared__ short Btl[3 * 48 * 40];
    int bi = blockIdx.x;
    int b = bi / 2500;
    int n0 = (bi % 2500) * 4;
    int tid = threadIdx.x;

    for (int j = tid; j < 384; j += 256) {
        int ci = j / 12, r = j - ci * 12;
        const float* xp = x + ((size_t)(b * CIN + ci) * NN + n0) * 12 + r * 4;
        float4 v = *(const float4*)xp;
        float vv[4] = {v.x, v.y, v.z, v.w};
#pragma unroll
        for (int e = 0; e < 4; ++e) {
            int at = r * 4 + e;
            int n = at / 12, t = at - n * 12;
            short bv = f2bf(vv[e]);
#pragma unroll
            for (int kk = 0; kk < 3; ++kk) {
                int tp = t + 1 - kk;
                if (tp >= 0 && tp < 12) {
                    int K = ci * 3 + kk;
                    Btl[((K >> 5) * 48 + n * 12 + tp) * 40 + (K & 31)] = bv;
                }
            }
            if (t == 0)  { int K = ci * 3;     Btl[((K >> 5) * 48 + n * 12) * 40 + (K & 31)] = 0; }
            if (t == 11) { int K = ci * 3 + 2; Btl[((K >> 5) * 48 + n * 12 + 11) * 40 + (K & 31)] = 0; }
        }
    }
    __syncthreads();

    int w = tid >> 6, l = tid & 63, lr = l & 15, lq = l >> 4;
    f32x4 aP[3], aQ[3];
#pragma unroll
    for (int m = 0; m < 3; ++m) { aP[m] = (f32x4){0,0,0,0}; aQ[m] = (f32x4){0,0,0,0}; }

#pragma unroll
    for (int ks = 0; ks < 3; ++ks) {
        bf16x8 wp = *(const bf16x8*)(wbf + ((w * 16 + lr) * 96 + ks * 32 + lq * 8));
        bf16x8 wq = *(const bf16x8*)(wbf + ((64 + w * 16 + lr) * 96 + ks * 32 + lq * 8));
#pragma unroll
        for (int mt = 0; mt < 3; ++mt) {
            bf16x8 im = *(const bf16x8*)(&Btl[(ks * 48 + mt * 16 + lr) * 40 + lq * 8]);
            aP[mt] = __builtin_amdgcn_mfma_f32_16x16x32_bf16(im, wp, aP[mt], 0, 0, 0);
            aQ[mt] = __builtin_amdgcn_mfma_f32_16x16x32_bf16(im, wq, aQ[mt], 0, 0, 0);
        }
    }

    int c = w * 16 + lr;
    float bp = bg[c], bq = bg[64 + c];
    float sc = gam[c] * rsqrtf(var[c] + EPSV);
    float mn = mean[c], be = bet[c];
#pragma unroll
    for (int mt = 0; mt < 3; ++mt) {
#pragma unroll
        for (int j = 0; j < 4; ++j) {
            int row = mt * 16 + lq * 4 + j;
            int n = n0 + row / 12, t = row % 12;
            float h = (aP[mt][j] + bp) * sigmoidf_(aQ[mt][j] + bq);
            h1[((size_t)(b * TTT + t) * NN + n) * 64 + c] = (ushort)f2bf((h - mn) * sc + be);
        }
    }
}

// ---------------- fused gather1 + Cheb einsum (MFMA), XCD-pinned ----------------
// grid = 15072 = 8 xcd * 12 snapshots * 157 chunks; 16 lanes per node, 4ch/lane
__global__ __launch_bounds__(256, 6) void k_spatial(
    const ushort* __restrict__ h1, const int* __restrict__ offs,
    const int2* __restrict__ csr,
    const short* __restrict__ wt02, const short* __restrict__ wt1,
    const short* __restrict__ wt2, const float* __restrict__ cb,
    ushort* __restrict__ O, ushort* __restrict__ U)
{
    __shared__ short Al[64][72];
    __shared__ short Gl[64][72];
    int tid = threadIdx.x;
    int bi = blockIdx.x;
    int xcd = bi & 7, j = bi >> 3;          // XCD-pinned snapshot schedule
    int bt = xcd * 12 + j / 157;
    int n0 = (j % 157) * 64;

    const ushort* hb = h1 + (size_t)bt * NN * 64;
    int w = tid >> 6, l = tid & 63;
    int qw = l >> 4, cp = l & 15;           // quarter-wave node, 4ch per lane

#pragma unroll
    for (int p = 0; p < 4; ++p) {
        int nl = p * 16 + w * 4 + qw;
        int n = n0 + nl;
        float4 va = {0,0,0,0}, vb = va, vc = va, vd = va;
        uint2 sv = {0u, 0u};
        if (n < NN) {
            sv = *(const uint2*)(hb + (size_t)n * 64 + cp * 4);
            int o0 = offs[n], o1 = offs[n + 1];
            int i = o0;
            for (; i + 3 < o1; i += 4) {
                int2 e0 = csr[i], e1 = csr[i + 1], e2 = csr[i + 2], e3 = csr[i + 3];
                uint2 r0 = *(const uint2*)(hb + (size_t)e0.x * 64 + cp * 4);
                uint2 r1 = *(const uint2*)(hb + (size_t)e1.x * 64 + cp * 4);
                uint2 r2 = *(const uint2*)(hb + (size_t)e2.x * 64 + cp * 4);
                uint2 r3 = *(const uint2*)(hb + (size_t)e3.x * 64 + cp * 4);
                float w0 = __int_as_float(e0.y), w1 = __int_as_float(e1.y);
                float w2 = __int_as_float(e2.y), w3 = __int_as_float(e3.y);
                va.x = fmaf(w0, lo16f(r0.x), va.x); va.y = fmaf(w0, hi16f(r0.x), va.y);
                va.z = fmaf(w0, lo16f(r0.y), va.z); va.w = fmaf(w0, hi16f(r0.y), va.w);
                vb.x = fmaf(w1, lo16f(r1.x), vb.x); vb.y = fmaf(w1, hi16f(r1.x), vb.y);
                vb.z = fmaf(w1, lo16f(r1.y), vb.z); vb.w = fmaf(w1, hi16f(r1.y), vb.w);
                vc.x = fmaf(w2, lo16f(r2.x), vc.x); vc.y = fmaf(w2, hi16f(r2.x), vc.y);
                vc.z = fmaf(w2, lo16f(r2.y), vc.z); vc.w = fmaf(w2, hi16f(r2.y), vc.w);
                vd.x = fmaf(w3, lo16f(r3.x), vd.x); vd.y = fmaf(w3, hi16f(r3.x), vd.y);
                vd.z = fmaf(w3, lo16f(r3.y), vd.z); vd.w = fmaf(w3, hi16f(r3.y), vd.w);
            }
            for (; i < o1; ++i) {
                int2 e = csr[i];
                uint2 r = *(const uint2*)(hb + (size_t)e.x * 64 + cp * 4);
                float ww = __int_as_float(e.y);
                va.x = fmaf(ww, lo16f(r.x), va.x); va.y = fmaf(ww, hi16f(r.x), va.y);
                va.z = fmaf(ww, lo16f(r.y), va.z); va.w = fmaf(ww, hi16f(r.y), va.w);
            }
        }
        float ax = (va.x + vb.x) + (vc.x + vd.x);
        float ay = (va.y + vb.y) + (vc.y + vd.y);
        float az = (va.z + vb.z) + (vc.z + vd.z);
        float aw = (va.w + vb.w) + (vc.w + vd.w);
        *(uint2*)&Al[nl][cp * 4] = sv;
        uint2 gp = { packbf(ax, ay), packbf(az, aw) };
        *(uint2*)&Gl[nl][cp * 4] = gp;
    }
    __syncthreads();

    int lr = l & 15, lq = l >> 4;
    bf16x8 af[2], gf[2];
#pragma unroll
    for (int ks = 0; ks < 2; ++ks) {
        af[ks] = *(const bf16x8*)&Al[w * 16 + lr][ks * 32 + lq * 8];
        gf[ks] = *(const bf16x8*)&Gl[w * 16 + lr][ks * 32 + lq * 8];
    }
    f32x4 ao[4], au[4];
#pragma unroll
    for (int ct = 0; ct < 4; ++ct) { ao[ct] = (f32x4){0,0,0,0}; au[ct] = (f32x4){0,0,0,0}; }
#pragma unroll
    for (int ct = 0; ct < 4; ++ct) {
#pragma unroll
        for (int ks = 0; ks < 2; ++ks) {
            int woff = (ct * 16 + lr) * 64 + ks * 32 + lq * 8;
            bf16x8 b02 = *(const bf16x8*)(wt02 + woff);
            bf16x8 b1  = *(const bf16x8*)(wt1 + woff);
            bf16x8 b2  = *(const bf16x8*)(wt2 + woff);
            ao[ct] = __builtin_amdgcn_mfma_f32_16x16x32_bf16(af[ks], b02, ao[ct], 0, 0, 0);
            ao[ct] = __builtin_amdgcn_mfma_f32_16x16x32_bf16(gf[ks], b1,  ao[ct], 0, 0, 0);
            au[ct] = __builtin_amdgcn_mfma_f32_16x16x32_bf16(gf[ks], b2,  au[ct], 0, 0, 0);
        }
    }
    __syncthreads();   // all frag reads done before overwriting Al/Gl

#pragma unroll
    for (int ct = 0; ct < 4; ++ct) {
        float bb = cb[ct * 16 + lr];
#pragma unroll
        for (int j2 = 0; j2 < 4; ++j2) {
            int node = w * 16 + lq * 4 + j2;
            Al[node][ct * 16 + lr] = f2bf(ao[ct][j2] + bb);
            Gl[node][ct * 16 + lr] = f2bf(au[ct][j2]);
        }
    }
    __syncthreads();

    size_t obase = (size_t)bt * NN * 64 + (size_t)n0 * 64;
#pragma unroll
    for (int r = 0; r < 2; ++r) {
        int idx = tid + r * 256;
        int node = idx >> 3, seg = idx & 7;
        if (n0 + node < NN) {
            *(bf16x8*)(O + obase + node * 64 + seg * 8) = *(const bf16x8*)&Al[node][seg * 8];
            *(bf16x8*)(U + obase + node * 64 + seg * 8) = *(const bf16x8*)&Gl[node][seg * 8];
        }
    }
}

// ---------------- gather 2 + LayerNorm + ReLU -> hln bf16, XCD-pinned ----------------
// grid = 60000 = 8 xcd * 12 snapshots * 625 chunks of 16 nodes
__global__ __launch_bounds__(256, 6) void k_gather2_ln(
    const ushort* __restrict__ O, const ushort* __restrict__ U,
    const int* __restrict__ offs, const int2* __restrict__ csr,
    const float* __restrict__ lng, const float* __restrict__ lnb,
    ushort* __restrict__ hln)
{
    int bi = blockIdx.x;
    int xcd = bi & 7, jj = bi >> 3;
    int bt = xcd * 12 + jj / 625;
    int ng = (jj % 625) * 16;
    int tid = threadIdx.x;
    int w = tid >> 6, l = tid & 63;
    int qw = l >> 4, cp = l & 15;
    int n = ng + w * 4 + qw;
    const ushort* Ub = U + (size_t)bt * NN * 64;
    size_t sidx = (size_t)bt * NN * 64 + (size_t)n * 64 + cp * 4;

    float4 va = {0,0,0,0}, vb = va, vc = va, vd = va;
    int o0 = offs[n], o1 = offs[n + 1];
    int i = o0;
    for (; i + 3 < o1; i += 4) {
        int2 e0 = csr[i], e1 = csr[i + 1], e2 = csr[i + 2], e3 = csr[i + 3];
        uint2 r0 = *(const uint2*)(Ub + (size_t)e0.x * 64 + cp * 4);
        uint2 r1 = *(const uint2*)(Ub + (size_t)e1.x * 64 + cp * 4);
        uint2 r2 = *(const uint2*)(Ub + (size_t)e2.x * 64 + cp * 4);
        uint2 r3 = *(const uint2*)(Ub + (size_t)e3.x * 64 + cp * 4);
        float w0 = __int_as_float(e0.y), w1 = __int_as_float(e1.y);
        float w2 = __int_as_float(e2.y), w3 = __int_as_float(e3.y);
        va.x = fmaf(w0, lo16f(r0.x), va.x); va.y = fmaf(w0, hi16f(r0.x), va.y);
        va.z = fmaf(w0, lo16f(r0.y), va.z); va.w = fmaf(w0, hi16f(r0.y), va.w);
        vb.x = fmaf(w1, lo16f(r1.x), vb.x); vb.y = fmaf(w1, hi16f(r1.x), vb.y);
        vb.z = fmaf(w1, lo16f(r1.y), vb.z); vb.w = fmaf(w1, hi16f(r1.y), vb.w);
        vc.x = fmaf(w2, lo16f(r2.x), vc.x); vc.y = fmaf(w2, hi16f(r2.x), vc.y);
        vc.z = fmaf(w2, lo16f(r2.y), vc.z); vc.w = fmaf(w2, hi16f(r2.y), vc.w);
        vd.x = fmaf(w3, lo16f(r3.x), vd.x); vd.y = fmaf(w3, hi16f(r3.x), vd.y);
        vd.z = fmaf(w3, lo16f(r3.y), vd.z); vd.w = fmaf(w3, hi16f(r3.y), vd.w);
    }
    for (; i < o1; ++i) {
        int2 e = csr[i];
        uint2 r = *(const uint2*)(Ub + (size_t)e.x * 64 + cp * 4);
        float ww = __int_as_float(e.y);
        va.x = fmaf(ww, lo16f(r.x), va.x); va.y = fmaf(ww, hi16f(r.x), va.y);
        va.z = fmaf(ww, lo16f(r.y), va.z); va.w = fmaf(ww, hi16f(r.y), va.w);
    }
    uint2 ov = *(const uint2*)(O + sidx);
    float acc0 = lo16f(ov.x) + 2.f * ((va.x + vb.x) + (vc.x + vd.x));
    float acc1 = hi16f(ov.x) + 2.f * ((va.y + vb.y) + (vc.y + vd.y));
    float acc2 = lo16f(ov.y) + 2.f * ((va.z + vb.z) + (vc.z + vd.z));
    float acc3 = hi16f(ov.y) + 2.f * ((va.w + vb.w) + (vc.w + vd.w));

    float s1 = (acc0 + acc1) + (acc2 + acc3);
    float s2 = (acc0 * acc0 + acc1 * acc1) + (acc2 * acc2 + acc3 * acc3);
#pragma unroll
    for (int m = 8; m >= 1; m >>= 1) {
        s1 += __shfl_xor(s1, m);
        s2 += __shfl_xor(s2, m);
    }
    float mu = s1 * (1.f / 64.f);
    float vr = s2 * (1.f / 64.f) - mu * mu;
    float rstd = rsqrtf(vr + EPSV);
    float4 g = *(const float4*)(lng + cp * 4);
    float4 be = *(const float4*)(lnb + cp * 4);
    float y0 = fmaxf((acc0 - mu) * rstd * g.x + be.x, 0.f);
    float y1 = fmaxf((acc1 - mu) * rstd * g.y + be.y, 0.f);
    float y2 = fmaxf((acc2 - mu) * rstd * g.z + be.z, 0.f);
    float y3 = fmaxf((acc3 - mu) * rstd * g.w + be.w, 0.f);
    uint2 pk = { packbf(y0, y1), packbf(y2, y3) };
    *(uint2*)(hln + sidx) = pk;
}

// ---------------- temporal block 2 + residual (MFMA) ----------------
__global__ __launch_bounds__(256, 4) void k_tconv2_mfma(
    const ushort* __restrict__ hln, const float* __restrict__ x,
    const short* __restrict__ wbf, const short* __restrict__ wrbf,
    const float* __restrict__ bg, const float* __restrict__ gam,
    const float* __restrict__ bet, const float* __restrict__ mean,
    const float* __restrict__ var, const float* __restrict__ bres,
    float* __restrict__ out)
{
    __shared__ short Btl[6 * 48 * 40];
    __shared__ short Bx[48 * 40];
    int bi = blockIdx.x;
    int b = bi / 2500;
    int n0 = (bi % 2500) * 4;
    int tid = threadIdx.x;

    {
        int n = tid >> 6, c = tid & 63;
#pragma unroll
        for (int t = 0; t < 12; ++t) {
            short bv = (short)hln[((size_t)(b * TTT + t) * NN + n0 + n) * 64 + c];
#pragma unroll
            for (int kk = 0; kk < 3; ++kk) {
                int tp = t + 1 - kk;
                if (tp >= 0 && tp < 12) {
                    int K = c * 3 + kk;
                    Btl[((K >> 5) * 48 + n * 12 + tp) * 40 + (K & 31)] = bv;
                }
            }
            if (t == 0)  { int K = c * 3;     Btl[((K >> 5) * 48 + n * 12) * 40 + (K & 31)] = 0; }
            if (t == 11) { int K = c * 3 + 2; Btl[((K >> 5) * 48 + n * 12 + 11) * 40 + (K & 31)] = 0; }
        }
    }
    for (int j = tid; j < 384; j += 256) {
        int ci = j / 12, r = j - ci * 12;
        const float* xp = x + ((size_t)(b * CIN + ci) * NN + n0) * 12 + r * 4;
        float4 v = *(const float4*)xp;
        float vv[4] = {v.x, v.y, v.z, v.w};
#pragma unroll
        for (int e = 0; e < 4; ++e) {
            int col = r * 4 + e;
            Bx[col * 40 + ci] = f2bf(vv[e]);
        }
    }
    __syncthreads();

    int w = tid >> 6, l = tid & 63, lr = l & 15, lq = l >> 4;
    f32x4 accP[3], accQ[3], accR[3];
#pragma unroll
    for (int m = 0; m < 3; ++m) {
        accP[m] = (f32x4){0,0,0,0}; accQ[m] = (f32x4){0,0,0,0}; accR[m] = (f32x4){0,0,0,0};
    }

#pragma unroll
    for (int ks = 0; ks < 6; ++ks) {
        bf16x8 aP = *(const bf16x8*)(wbf + ((w * 16 + lr) * 192 + ks * 32 + lq * 8));
        bf16x8 aQ = *(const bf16x8*)(wbf + ((64 + w * 16 + lr) * 192 + ks * 32 + lq * 8));
#pragma unroll
        for (int ct = 0; ct < 3; ++ct) {
            bf16x8 bfr = *(const bf16x8*)(&Btl[(ks * 48 + ct * 16 + lr) * 40 + lq * 8]);
            accP[ct] = __builtin_amdgcn_mfma_f32_16x16x32_bf16(aP, bfr, accP[ct], 0, 0, 0);
            accQ[ct] = __builtin_amdgcn_mfma_f32_16x16x32_bf16(aQ, bfr, accQ[ct], 0, 0, 0);
        }
    }
    {
        bf16x8 aR = *(const bf16x8*)(wrbf + ((w * 16 + lr) * 32 + lq * 8));
#pragma unroll
        for (int ct = 0; ct < 3; ++ct) {
            bf16x8 bx = *(const bf16x8*)(&Bx[(ct * 16 + lr) * 40 + lq * 8]);
            accR[ct] = __builtin_amdgcn_mfma_f32_16x16x32_bf16(aR, bx, accR[ct], 0, 0, 0);
        }
    }

    float bpv[4], bqv[4], scv[4], mnv[4], bev[4], brv[4];
#pragma unroll
    for (int j = 0; j < 4; ++j) {
        int cj = w * 16 + lq * 4 + j;
        bpv[j] = bg[cj]; bqv[j] = bg[64 + cj];
        scv[j] = gam[cj] * rsqrtf(var[cj] + EPSV);
        mnv[j] = mean[cj]; bev[j] = bet[cj]; brv[j] = bres[cj];
    }
#pragma unroll
    for (int ct = 0; ct < 3; ++ct) {
        int col = ct * 16 + lr;
        int n = n0 + col / 12, t = col % 12;
#pragma unroll
        for (int j = 0; j < 4; ++j) {
            int cj = w * 16 + lq * 4 + j;
            float h = (accP[ct][j] + bpv[j]) * sigmoidf_(accQ[ct][j] + bqv[j]);
            float o = (h - mnv[j]) * scv[j] + bev[j] + accR[ct][j] + brv[j];
            out[((size_t)(b * 64 + cj) * NN + n) * 12 + t] = o;
        }
    }
}

extern "C" void kernel_launch(void* const* d_in, const int* in_sizes, int n_in,
                              void* d_out, int out_size, void* d_ws, size_t ws_size,
                              hipStream_t stream)
{
    const float* x   = (const float*)d_in[0];
    const int*   ei  = (const int*)d_in[1];
    const float* ew  = (const float*)d_in[2];
    const float* wg1 = (const float*)d_in[3];
    const float* bg1 = (const float*)d_in[4];
    const float* g1  = (const float*)d_in[5];
    const float* be1 = (const float*)d_in[6];
    const float* m1  = (const float*)d_in[7];
    const float* v1  = (const float*)d_in[8];
    const float* cw  = (const float*)d_in[9];
    const float* cb  = (const float*)d_in[10];
    const float* lng = (const float*)d_in[11];
    const float* lnb = (const float*)d_in[12];
    const float* wg2 = (const float*)d_in[13];
    const float* bg2 = (const float*)d_in[14];
    const float* g2  = (const float*)d_in[15];
    const float* be2 = (const float*)d_in[16];
    const float* m2  = (const float*)d_in[17];
    const float* v2  = (const float*)d_in[18];
    const float* wr  = (const float*)d_in[19];
    const float* br  = (const float*)d_in[20];

    char* w = (char*)d_ws;
    short* wbf1  = (short*)w;  w += 12288 * 2;
    short* wbf2  = (short*)w;  w += 24576 * 2;
    short* wrbf  = (short*)w;  w += 2048 * 2;
    short* wt02  = (short*)w;  w += 4096 * 2;
    short* wt1   = (short*)w;  w += 4096 * 2;
    short* wt2   = (short*)w;  w += 4096 * 2;
    ushort* h1   = (ushort*)w; w += (size_t)BT * NN * 64 * 2;   // 122.88 MB (reused as hln)
    ushort* O    = (ushort*)w; w += (size_t)BT * NN * 64 * 2;   // 122.88 MB
    float* deg   = (float*)w;  w += NN * 4;
    int*   cnt   = (int*)w;    w += NN * 4;
    int*   offs  = (int*)w;    w += (NN + 1) * 4;
    int*   cursor= (int*)w;    w += NN * 4;
    float* nrm   = (float*)w;  w += EE * 4;
    w = (char*)(((size_t)w + 15) & ~(size_t)15);
    int2*  csr   = (int2*)w;   w += EE * 8;
    ushort* U = (ushort*)d_out;   // reuse output buffer as U field (bf16)

    hipMemsetAsync(deg, 0, NN * 4 * 2, stream);   // deg + cnt

    k_deg<<<625, 256, 0, stream>>>(ei, ew, deg);
    k_dinv<<<40, 256, 0, stream>>>(deg);
    k_norm_cnt<<<625, 256, 0, stream>>>(ei, ew, deg, nrm, cnt);
    k_scan<<<1, 1024, 0, stream>>>(cnt, offs, cursor);
    k_fill<<<625, 256, 0, stream>>>(ei, nrm, cursor, csr);
    k_cvt_w<<<96, 256, 0, stream>>>(wg1, wg2, wr, cw, wbf1, wbf2, wrbf, wt02, wt1, wt2);

    k_tconv1_mfma<<<BB * 2500, 256, 0, stream>>>(x, wbf1, bg1, g1, be1, m1, v1, h1);
    k_spatial<<<BT * 157, 256, 0, stream>>>(h1, offs, csr, wt02, wt1, wt2, cb, O, U);
    k_gather2_ln<<<60000, 256, 0, stream>>>(O, U, offs, csr, lng, lnb, h1);
    k_tconv2_mfma<<<BB * 2500, 256, 0, stream>>>(h1, x, wbf2, wrbf, bg2, g2, be2, m2, v2, br,
                                                 (float*)d_out);
}